// Round 2
// 810.911 us; speedup vs baseline: 1.2571x; 1.2571x over previous
//
#include <hip/hip_runtime.h>
#include <hip/hip_bf16.h>

#define NODE_F 74
#define HID 128
#define DIM 256

typedef __hip_bfloat16 bf16;
typedef unsigned int u32;
typedef unsigned short u16;

typedef short s16x8 __attribute__((ext_vector_type(8)));
typedef __bf16 bf16x8 __attribute__((ext_vector_type(8)));
typedef float f32x4 __attribute__((ext_vector_type(4)));

__device__ __forceinline__ float rdl(float v, int l){
  return __int_as_float(__builtin_amdgcn_readlane(__float_as_int(v), l));
}
__device__ __forceinline__ float2 bfpair(u32 u){
  float2 r;
  r.x = __uint_as_float(u << 16);
  r.y = __uint_as_float(u & 0xffff0000u);
  return r;
}
__device__ __forceinline__ u16 bfbits(float a){
  return __bfloat16_as_ushort(__float2bfloat16(a));
}

// ---------------- degrees ----------------
__global__ void k_deg(const int* __restrict__ src, const int* __restrict__ dst,
                      float* __restrict__ outdeg_f, int* __restrict__ indeg, int E_){
  int e = blockIdx.x*256 + threadIdx.x;
  if (e < E_){
    atomicAdd(&outdeg_f[src[e]], 1.0f);
    atomicAdd(&indeg[dst[e]], 1);
  }
}

__global__ void k_norm(float* __restrict__ norm_s, const int* __restrict__ indeg,
                       float* __restrict__ norm_d, int n){
  int i = blockIdx.x*256 + threadIdx.x;
  if (i < n){
    norm_s[i] = rsqrtf(fmaxf(norm_s[i], 1.0f));
    norm_d[i] = rsqrtf(fmaxf((float)indeg[i], 1.0f));
  }
}

// ---------------- CSR build ----------------
__global__ __launch_bounds__(1024) void k_scan(int* __restrict__ indeg,
                                               int* __restrict__ row_ptr, int n){
  __shared__ int part[1024];
  const int T = 1024;
  const int tid = threadIdx.x;
  const int chunk = (n + T - 1) / T;
  const int lo = tid*chunk;
  const int hi = (lo + chunk < n) ? lo + chunk : n;
  int s = 0;
  for (int i = lo; i < hi; ++i) s += indeg[i];
  part[tid] = s;
  __syncthreads();
  for (int off = 1; off < T; off <<= 1){
    int v = (tid >= off) ? part[tid-off] : 0;
    __syncthreads();
    part[tid] += v;
    __syncthreads();
  }
  int run = (tid == 0) ? 0 : part[tid-1];
  for (int i = lo; i < hi; ++i){
    int c = indeg[i];
    row_ptr[i] = run;
    run += c;
    indeg[i] = 0;            // becomes cursor for k_fill
  }
  if (tid == T-1) row_ptr[n] = run;
}

__global__ void k_fill(const int* __restrict__ src, const int* __restrict__ dst,
                       const int* __restrict__ row_ptr, int* __restrict__ cursor,
                       int* __restrict__ col, int E_){
  int e = blockIdx.x*256 + threadIdx.x;
  if (e < E_){
    int d = dst[e];
    int pos = row_ptr[d] + atomicAdd(&cursor[d], 1);
    col[pos] = src[e];
  }
}

// ---------------- weight prepack: fp32 [K x 128] -> bf16 MFMA fragment order
// dst[((t*S + s)*64 + lane)*8 + e] = W[s*32 + (lane>>4)*8 + e][t*16 + (lane&15)]
__global__ void k_prep(const float* __restrict__ W, u16* __restrict__ dst,
                       int S, int Ktrue){
  int idx = blockIdx.x*256 + threadIdx.x;
  const int tot = 8*S*512;
  if (idx >= tot) return;
  const int e   = idx & 7;
  const int l   = (idx >> 3) & 63;
  const int rem = idx >> 9;
  const int s   = rem % S;
  const int t   = rem / S;
  const int k   = s*32 + (l >> 4)*8 + e;
  const int c   = t*16 + (l & 15);
  const float v = (k < Ktrue) ? W[(size_t)k*HID + c] : 0.f;
  dst[idx] = bfbits(v);
}

// ---------------- fused layer 1: gather(x0) -> dual MFMA -> h1 (bf16) ----------------
// Wave tile: rows r0..r0+15. Lane (jg,kg) gathers A[r0+jg][k], k = s*32+kg*8+e (K=96 pad).
// D: col = t*16 + jg, row = r0 + 4*kg + r.
__global__ __launch_bounds__(256) void k_fgemm1(
    const float* __restrict__ x0, const int* __restrict__ row_ptr,
    const int* __restrict__ col, const float* __restrict__ norm_s,
    const float* __restrict__ norm_d,
    const u16* __restrict__ Bp, const float* __restrict__ bg_,
    const float* __restrict__ br_, u16* __restrict__ h1, int n){
  const int lane = threadIdx.x & 63;
  const int wid  = threadIdx.x >> 6;
  const int jg = lane & 15, kg = lane >> 4;
  const int r0 = blockIdx.x*64 + wid*16;
  const int row = r0 + jg;
  const bool rok = row < n;
  const int kb = kg*8;

  float agg[3][8];
  #pragma unroll
  for (int s = 0; s < 3; ++s)
    #pragma unroll
    for (int e = 0; e < 8; ++e) agg[s][e] = 0.f;

  int p0 = 0, p1 = 0;
  if (rok){ p0 = row_ptr[row]; p1 = row_ptr[row+1]; }
  for (int p = p0; p < p1; ++p){
    const int sc = col[p];
    const float ns = norm_s[sc];
    const float* px = x0 + (size_t)sc*NODE_F;
    #pragma unroll
    for (int s = 0; s < 2; ++s){
      #pragma unroll
      for (int e = 0; e < 8; e += 2){
        const float2 v = *(const float2*)&px[s*32 + kb + e];
        agg[s][e]   = fmaf(v.x, ns, agg[s][e]);
        agg[s][e+1] = fmaf(v.y, ns, agg[s][e+1]);
      }
    }
    if (kg == 0){
      #pragma unroll
      for (int e = 0; e < 8; e += 2){
        const float2 v = *(const float2*)&px[64 + e];
        agg[2][e]   = fmaf(v.x, ns, agg[2][e]);
        agg[2][e+1] = fmaf(v.y, ns, agg[2][e+1]);
      }
    } else if (kg == 1){
      const float2 v = *(const float2*)&px[72];
      agg[2][0] = fmaf(v.x, ns, agg[2][0]);
      agg[2][1] = fmaf(v.y, ns, agg[2][1]);
    }
  }

  const float nd = rok ? norm_d[row] : 0.f;
  bf16x8 ag[3], ar[3];
  #pragma unroll
  for (int s = 0; s < 3; ++s)
    #pragma unroll
    for (int e = 0; e < 8; ++e) ag[s][e] = (__bf16)(agg[s][e]*nd);

  {
    const int rA = rok ? row : (n-1);
    const float* px = x0 + (size_t)rA*NODE_F;
    #pragma unroll
    for (int s = 0; s < 2; ++s)
      #pragma unroll
      for (int e = 0; e < 8; e += 2){
        const float2 w = *(const float2*)&px[s*32 + kb + e];
        ar[s][e]   = (__bf16)w.x;
        ar[s][e+1] = (__bf16)w.y;
      }
    #pragma unroll
    for (int e = 0; e < 8; ++e) ar[2][e] = (__bf16)0.f;
    if (kg == 0){
      #pragma unroll
      for (int e = 0; e < 8; e += 2){
        const float2 w = *(const float2*)&px[64 + e];
        ar[2][e]   = (__bf16)w.x;
        ar[2][e+1] = (__bf16)w.y;
      }
    } else if (kg == 1){
      const float2 w = *(const float2*)&px[72];
      ar[2][0] = (__bf16)w.x;
      ar[2][1] = (__bf16)w.y;
    }
  }

  f32x4 accg[8], accr[8];
  #pragma unroll
  for (int t = 0; t < 8; ++t){
    accg[t] = f32x4{0.f,0.f,0.f,0.f};
    accr[t] = f32x4{0.f,0.f,0.f,0.f};
  }
  constexpr int FR1 = 8*3*512;
  #pragma unroll
  for (int s = 0; s < 3; ++s){
    #pragma unroll
    for (int t = 0; t < 8; ++t){
      const bf16x8 bg = __builtin_bit_cast(bf16x8,
          *(const s16x8*)&Bp[((t*3 + s)*64 + lane)*8]);
      const bf16x8 br = __builtin_bit_cast(bf16x8,
          *(const s16x8*)&Bp[FR1 + ((t*3 + s)*64 + lane)*8]);
      accg[t] = __builtin_amdgcn_mfma_f32_16x16x32_bf16(ag[s], bg, accg[t], 0,0,0);
      accr[t] = __builtin_amdgcn_mfma_f32_16x16x32_bf16(ar[s], br, accr[t], 0,0,0);
    }
  }

  const int rowb = r0 + 4*kg;
  #pragma unroll
  for (int t = 0; t < 8; ++t){
    const int colc = t*16 + jg;
    const float bgv = bg_[colc], brv = br_[colc];
    #pragma unroll
    for (int r = 0; r < 4; ++r){
      const int row2 = rowb + r;
      if (row2 < n){
        const float o = fmaxf(accg[t][r] + bgv, 0.f) + fmaxf(accr[t][r] + brv, 0.f);
        h1[(size_t)row2*HID + colc] = bfbits(o);
      }
    }
  }
}

// ---------------- fused layer 2 + readout: gather(h1) -> dual MFMA -> atomic hsum/hmax
__global__ __launch_bounds__(256) void k_fgemm2(
    const u16* __restrict__ h1, const int* __restrict__ row_ptr,
    const int* __restrict__ col, const float* __restrict__ norm_s,
    const float* __restrict__ norm_d,
    const u16* __restrict__ Bp, const float* __restrict__ bg_,
    const float* __restrict__ br_,
    const float* __restrict__ w_atom, const float* __restrict__ b_atom,
    const int* __restrict__ gid,
    float* __restrict__ hsum, u32* __restrict__ hmax, int n){
  const int lane = threadIdx.x & 63;
  const int wid  = threadIdx.x >> 6;
  const int jg = lane & 15, kg = lane >> 4;
  const int r0 = blockIdx.x*64 + wid*16;
  const int row = r0 + jg;
  const bool rok = row < n;
  const int kb = kg*8;

  float agg[4][8];
  #pragma unroll
  for (int s = 0; s < 4; ++s)
    #pragma unroll
    for (int e = 0; e < 8; ++e) agg[s][e] = 0.f;

  int p0 = 0, p1 = 0;
  if (rok){ p0 = row_ptr[row]; p1 = row_ptr[row+1]; }
  for (int p = p0; p < p1; ++p){
    const int sc = col[p];
    const float ns = norm_s[sc];
    const u16* ph = h1 + (size_t)sc*HID + kb;
    #pragma unroll
    for (int s = 0; s < 4; ++s){
      const uint4 v = *(const uint4*)(ph + s*32);
      const float2 f0 = bfpair(v.x), f1 = bfpair(v.y);
      const float2 f2 = bfpair(v.z), f3 = bfpair(v.w);
      agg[s][0] = fmaf(f0.x, ns, agg[s][0]);
      agg[s][1] = fmaf(f0.y, ns, agg[s][1]);
      agg[s][2] = fmaf(f1.x, ns, agg[s][2]);
      agg[s][3] = fmaf(f1.y, ns, agg[s][3]);
      agg[s][4] = fmaf(f2.x, ns, agg[s][4]);
      agg[s][5] = fmaf(f2.y, ns, agg[s][5]);
      agg[s][6] = fmaf(f3.x, ns, agg[s][6]);
      agg[s][7] = fmaf(f3.y, ns, agg[s][7]);
    }
  }

  const float nd = rok ? norm_d[row] : 0.f;
  bf16x8 ag[4];
  #pragma unroll
  for (int s = 0; s < 4; ++s)
    #pragma unroll
    for (int e = 0; e < 8; ++e) ag[s][e] = (__bf16)(agg[s][e]*nd);

  const int rA = rok ? row : (n-1);
  const u16* phr = h1 + (size_t)rA*HID + kb;

  f32x4 accg[8], accr[8];
  #pragma unroll
  for (int t = 0; t < 8; ++t){
    accg[t] = f32x4{0.f,0.f,0.f,0.f};
    accr[t] = f32x4{0.f,0.f,0.f,0.f};
  }
  constexpr int FR2 = 8*4*512;
  #pragma unroll
  for (int s = 0; s < 4; ++s){
    const bf16x8 arf = __builtin_bit_cast(bf16x8, *(const s16x8*)(phr + s*32));
    #pragma unroll
    for (int t = 0; t < 8; ++t){
      const bf16x8 bg = __builtin_bit_cast(bf16x8,
          *(const s16x8*)&Bp[((t*4 + s)*64 + lane)*8]);
      const bf16x8 br = __builtin_bit_cast(bf16x8,
          *(const s16x8*)&Bp[FR2 + ((t*4 + s)*64 + lane)*8]);
      accg[t] = __builtin_amdgcn_mfma_f32_16x16x32_bf16(ag[s], bg, accg[t], 0,0,0);
      accr[t] = __builtin_amdgcn_mfma_f32_16x16x32_bf16(arf, br, accr[t], 0,0,0);
    }
  }

  // epilogue: h2 values in registers -> fused WeightedSumAndMax readout
  float o[8][4];
  #pragma unroll
  for (int t = 0; t < 8; ++t){
    const int colc = t*16 + jg;
    const float bgv = bg_[colc], brv = br_[colc];
    #pragma unroll
    for (int r = 0; r < 4; ++r)
      o[t][r] = fmaxf(accg[t][r] + bgv, 0.f) + fmaxf(accr[t][r] + brv, 0.f);
  }
  float wa[8];
  #pragma unroll
  for (int t = 0; t < 8; ++t) wa[t] = w_atom[t*16 + jg];
  const float ba = b_atom[0];
  const int rowb = r0 + 4*kg;
  #pragma unroll
  for (int r = 0; r < 4; ++r){
    const int row2 = rowb + r;
    float dot = 0.f;
    #pragma unroll
    for (int t = 0; t < 8; ++t) dot = fmaf(o[t][r], wa[t], dot);
    dot += __shfl_xor(dot, 1);
    dot += __shfl_xor(dot, 2);
    dot += __shfl_xor(dot, 4);
    dot += __shfl_xor(dot, 8);
    if (row2 < n){
      const float aw = 1.0f/(1.0f + __expf(-(dot + ba)));
      const int g = gid[row2];
      #pragma unroll
      for (int t = 0; t < 8; ++t){
        const int colc = t*16 + jg;
        atomicAdd(&hsum[(size_t)g*HID + colc], o[t][r]*aw);
        atomicMax(&hmax[(size_t)g*HID + colc], __float_as_uint(o[t][r]));  // o >= 0
      }
    }
  }
}

// ---------------- MLP layer 1: hid = relu(concat(hsum,hmax) @ Wp1 + bp1) ----------------
__global__ __launch_bounds__(256) void k_mlp1(
    const float* __restrict__ hsum, const float* __restrict__ hmaxf,
    const float* __restrict__ Wp1, const float* __restrict__ bp1,
    float* __restrict__ hid, int G_){
  const int lane = threadIdx.x & 63;
  const int row = blockIdx.x*4 + (threadIdx.x >> 6);
  if (row >= G_) return;
  const int c = lane*2;
  float ra0 = hsum[(size_t)row*HID + lane];
  float ra1 = hsum[(size_t)row*HID + 64 + lane];
  float ra2 = hmaxf[(size_t)row*HID + lane];
  float ra3 = hmaxf[(size_t)row*HID + 64 + lane];
  float a0 = 0.f, a1 = 0.f;
  #pragma unroll 4
  for (int k = 0; k < 64; ++k){
    const float v0 = rdl(ra0,k), v1 = rdl(ra1,k), v2 = rdl(ra2,k), v3 = rdl(ra3,k);
    const float2 w0 = *(const float2*)&Wp1[(size_t)(k      )*HID + c];
    const float2 w1 = *(const float2*)&Wp1[(size_t)(k +  64)*HID + c];
    const float2 w2 = *(const float2*)&Wp1[(size_t)(k + 128)*HID + c];
    const float2 w3 = *(const float2*)&Wp1[(size_t)(k + 192)*HID + c];
    a0 = fmaf(v0,w0.x, fmaf(v1,w1.x, fmaf(v2,w2.x, fmaf(v3,w3.x, a0))));
    a1 = fmaf(v0,w0.y, fmaf(v1,w1.y, fmaf(v2,w2.y, fmaf(v3,w3.y, a1))));
  }
  hid[(size_t)row*HID + c]   = fmaxf(a0 + bp1[c],   0.f);
  hid[(size_t)row*HID + c+1] = fmaxf(a1 + bp1[c+1], 0.f);
}

// ---------------- MLP layer 2 + zero-row insertion ----------------
__global__ __launch_bounds__(256) void k_mlp2(
    const float* __restrict__ hid, const float* __restrict__ Wp2,
    const float* __restrict__ bp2, const int* __restrict__ idxw, int K_,
    float* __restrict__ out, int G_){
  const int lane = threadIdx.x & 63;
  const int row = blockIdx.x*4 + (threadIdx.x >> 6);
  if (row >= G_) return;
  const int c = lane*4;
  float ra0 = hid[(size_t)row*HID + lane];
  float ra1 = hid[(size_t)row*HID + 64 + lane];
  float acc0=0.f, acc1=0.f, acc2=0.f, acc3=0.f;
  #pragma unroll 4
  for (int k = 0; k < 64; ++k){
    const float a = rdl(ra0, k);
    const float4 w = *(const float4*)&Wp2[(size_t)k*DIM + c];
    acc0 = fmaf(a,w.x,acc0); acc1 = fmaf(a,w.y,acc1);
    acc2 = fmaf(a,w.z,acc2); acc3 = fmaf(a,w.w,acc3);
  }
  #pragma unroll 4
  for (int k = 64; k < 128; ++k){
    const float a = rdl(ra1, k-64);
    const float4 w = *(const float4*)&Wp2[(size_t)k*DIM + c];
    acc0 = fmaf(a,w.x,acc0); acc1 = fmaf(a,w.y,acc1);
    acc2 = fmaf(a,w.z,acc2); acc3 = fmaf(a,w.w,acc3);
  }
  int orow = row;
  for (int j = 0; j < K_; ++j){ if (idxw[j] <= orow) orow++; }
  float* po = out + (size_t)orow*DIM + c;
  po[0] = acc0 + bp2[c];
  po[1] = acc1 + bp2[c+1];
  po[2] = acc2 + bp2[c+2];
  po[3] = acc3 + bp2[c+3];
}

extern "C" void kernel_launch(void* const* d_in, const int* in_sizes, int n_in,
                              void* d_out, int out_size, void* d_ws, size_t ws_size,
                              hipStream_t stream){
  (void)n_in; (void)ws_size;
  const float* x0     = (const float*)d_in[0];
  // d_in[1] = edge_feats (unused by the reference GCN)
  const float* W1     = (const float*)d_in[2];
  const float* b1     = (const float*)d_in[3];
  const float* Wr1    = (const float*)d_in[4];
  const float* br1    = (const float*)d_in[5];
  const float* W2     = (const float*)d_in[6];
  const float* b2     = (const float*)d_in[7];
  const float* Wr2    = (const float*)d_in[8];
  const float* br2    = (const float*)d_in[9];
  const float* w_atom = (const float*)d_in[10];
  const float* b_atom = (const float*)d_in[11];
  const float* Wp1    = (const float*)d_in[12];
  const float* bp1    = (const float*)d_in[13];
  const float* Wp2    = (const float*)d_in[14];
  const float* bp2    = (const float*)d_in[15];
  const int* src  = (const int*)d_in[16];
  const int* dst  = (const int*)d_in[17];
  const int* gid  = (const int*)d_in[18];
  const int* idxw = (const int*)d_in[19];

  const int N_ = in_sizes[0] / NODE_F;
  const int E_ = in_sizes[16];
  const int K_ = in_sizes[19];
  const int G_ = out_size / DIM - K_;

  // workspace (~32.6 MB — identical footprint to the proven baseline):
  //  [h1 bf16 N*128][norm_s N][norm_d N][hsum G*128][hmax G*128][hid G*128]
  //  [indeg N][row_ptr N+1 pad][col E]
  u16*   h1     = (u16*)d_ws;                          // N*128 u16
  float* norm_s = (float*)(h1 + (size_t)N_*HID);
  float* norm_d = norm_s + N_;
  float* hsum   = norm_d + N_;
  float* hmaxv  = hsum + (size_t)G_*HID;
  float* hid    = hmaxv + (size_t)G_*HID;
  int*   indeg  = (int*)(hid + (size_t)G_*HID);
  int*   row_ptr= indeg + N_;
  int*   col    = row_ptr + ((N_ + 4) & ~3);
  // weight-fragment scratch lives in d_out's tail (2.56 MB total, frags = 112 KB);
  // d_out is memset AFTER k_fgemm2, before k_mlp2 writes it.
  u16*   Bp1    = (u16*)d_out;                         // 2*12288 u16
  u16*   Bp2    = Bp1 + 2*8*3*512;                     // 2*16384 u16

  hipMemsetAsync(norm_s, 0, (size_t)2*N_*sizeof(float), stream);
  hipMemsetAsync(hsum, 0, (size_t)2*G_*HID*sizeof(float), stream);
  hipMemsetAsync(indeg, 0, (size_t)N_*sizeof(int), stream);

  k_deg   <<<(E_+255)/256, 256, 0, stream>>>(src, dst, norm_s, indeg, E_);
  k_norm  <<<(N_+255)/256, 256, 0, stream>>>(norm_s, indeg, norm_d, N_);
  k_scan  <<<1, 1024, 0, stream>>>(indeg, row_ptr, N_);
  k_fill  <<<(E_+255)/256, 256, 0, stream>>>(src, dst, row_ptr, indeg, col, E_);

  k_prep<<<(8*3*512+255)/256, 256, 0, stream>>>(W1,  Bp1,            3, NODE_F);
  k_prep<<<(8*3*512+255)/256, 256, 0, stream>>>(Wr1, Bp1 + 8*3*512,  3, NODE_F);
  k_prep<<<(8*4*512+255)/256, 256, 0, stream>>>(W2,  Bp2,            4, HID);
  k_prep<<<(8*4*512+255)/256, 256, 0, stream>>>(Wr2, Bp2 + 8*4*512,  4, HID);

  const int nb = (N_ + 63) / 64;
  k_fgemm1<<<nb, 256, 0, stream>>>(x0, row_ptr, col, norm_s, norm_d,
                                   Bp1, b1, br1, h1, N_);
  k_fgemm2<<<nb, 256, 0, stream>>>(h1, row_ptr, col, norm_s, norm_d,
                                   Bp2, b2, br2, w_atom, b_atom, gid,
                                   hsum, (u32*)hmaxv, N_);

  // now safe to zero the output (weight frags no longer needed)
  hipMemsetAsync(d_out, 0, (size_t)out_size*sizeof(float), stream);

  k_mlp1<<<(G_+3)/4, 256, 0, stream>>>(hsum, hmaxv, Wp1, bp1, hid, G_);
  k_mlp2<<<(G_+3)/4, 256, 0, stream>>>(hid, Wp2, bp2, idxw, K_, (float*)d_out, G_);
}

// Round 3
// 584.010 us; speedup vs baseline: 1.7455x; 1.3885x over previous
//
#include <hip/hip_runtime.h>
#include <hip/hip_bf16.h>

#define NODE_F 74
#define HID 128
#define DIM 256

typedef __hip_bfloat16 bf16;
typedef unsigned int u32;
typedef unsigned short u16;

typedef short s16x8 __attribute__((ext_vector_type(8)));
typedef __bf16 bf16x8 __attribute__((ext_vector_type(8)));
typedef float f32x4 __attribute__((ext_vector_type(4)));

__device__ __forceinline__ float rdl(float v, int l){
  return __int_as_float(__builtin_amdgcn_readlane(__float_as_int(v), l));
}
__device__ __forceinline__ float2 bfpair(u32 u){
  float2 r;
  r.x = __uint_as_float(u << 16);
  r.y = __uint_as_float(u & 0xffff0000u);
  return r;
}
__device__ __forceinline__ u16 bfbits(float a){
  return __bfloat16_as_ushort(__float2bfloat16(a));
}

// ---------------- degrees ----------------
__global__ void k_deg(const int* __restrict__ src, const int* __restrict__ dst,
                      float* __restrict__ outdeg_f, int* __restrict__ indeg, int E_){
  int e = blockIdx.x*256 + threadIdx.x;
  if (e < E_){
    atomicAdd(&outdeg_f[src[e]], 1.0f);
    atomicAdd(&indeg[dst[e]], 1);
  }
}

__global__ void k_norm(float* __restrict__ norm_s, const int* __restrict__ indeg,
                       float* __restrict__ norm_d, int n){
  int i = blockIdx.x*256 + threadIdx.x;
  if (i < n){
    norm_s[i] = rsqrtf(fmaxf(norm_s[i], 1.0f));
    norm_d[i] = rsqrtf(fmaxf((float)indeg[i], 1.0f));
  }
}

// ---------------- CSR build ----------------
__global__ __launch_bounds__(1024) void k_scan(int* __restrict__ indeg,
                                               int* __restrict__ row_ptr, int n){
  __shared__ int part[1024];
  const int T = 1024;
  const int tid = threadIdx.x;
  const int chunk = (n + T - 1) / T;
  const int lo = tid*chunk;
  const int hi = (lo + chunk < n) ? lo + chunk : n;
  int s = 0;
  for (int i = lo; i < hi; ++i) s += indeg[i];
  part[tid] = s;
  __syncthreads();
  for (int off = 1; off < T; off <<= 1){
    int v = (tid >= off) ? part[tid-off] : 0;
    __syncthreads();
    part[tid] += v;
    __syncthreads();
  }
  int run = (tid == 0) ? 0 : part[tid-1];
  for (int i = lo; i < hi; ++i){
    int c = indeg[i];
    row_ptr[i] = run;
    run += c;
    indeg[i] = 0;            // becomes cursor for k_fill
  }
  if (tid == T-1) row_ptr[n] = run;
}

__global__ void k_fill(const int* __restrict__ src, const int* __restrict__ dst,
                       const int* __restrict__ row_ptr, int* __restrict__ cursor,
                       int* __restrict__ col, int E_){
  int e = blockIdx.x*256 + threadIdx.x;
  if (e < E_){
    int d = dst[e];
    int pos = row_ptr[d] + atomicAdd(&cursor[d], 1);
    col[pos] = src[e];
  }
}

// ---------------- weight prepack: fp32 [K x 128] -> bf16 MFMA fragment order
// dst[((t*S + s)*64 + lane)*8 + e] = W[s*32 + (lane>>4)*8 + e][t*16 + (lane&15)]
__global__ void k_prep(const float* __restrict__ W, u16* __restrict__ dst,
                       int S, int Ktrue){
  int idx = blockIdx.x*256 + threadIdx.x;
  const int tot = 8*S*512;
  if (idx >= tot) return;
  const int e   = idx & 7;
  const int l   = (idx >> 3) & 63;
  const int rem = idx >> 9;
  const int s   = rem % S;
  const int t   = rem / S;
  const int k   = s*32 + (l >> 4)*8 + e;
  const int c   = t*16 + (l & 15);
  const float v = (k < Ktrue) ? W[(size_t)k*HID + c] : 0.f;
  dst[idx] = bfbits(v);
}

// ---------------- fused layer 1: gather(x0) -> dual MFMA -> h1 (bf16) ----------------
// Wave tile: rows r0..r0+15. Lane (jg,kg) gathers A[r0+jg][k], k = s*32+kg*8+e (K=96 pad).
// D: col = t*16 + jg, row = r0 + 4*kg + r.
__global__ __launch_bounds__(256) void k_fgemm1(
    const float* __restrict__ x0, const int* __restrict__ row_ptr,
    const int* __restrict__ col, const float* __restrict__ norm_s,
    const float* __restrict__ norm_d,
    const u16* __restrict__ Bp, const float* __restrict__ bg_,
    const float* __restrict__ br_, u16* __restrict__ h1, int n){
  const int lane = threadIdx.x & 63;
  const int wid  = threadIdx.x >> 6;
  const int jg = lane & 15, kg = lane >> 4;
  const int r0 = blockIdx.x*64 + wid*16;
  const int row = r0 + jg;
  const bool rok = row < n;
  const int kb = kg*8;

  float agg[3][8];
  #pragma unroll
  for (int s = 0; s < 3; ++s)
    #pragma unroll
    for (int e = 0; e < 8; ++e) agg[s][e] = 0.f;

  auto accum = [&](const float* px, float ns){
    #pragma unroll
    for (int s = 0; s < 2; ++s){
      #pragma unroll
      for (int e = 0; e < 8; e += 2){
        const float2 v = *(const float2*)&px[s*32 + kb + e];
        agg[s][e]   = fmaf(v.x, ns, agg[s][e]);
        agg[s][e+1] = fmaf(v.y, ns, agg[s][e+1]);
      }
    }
    if (kg == 0){
      #pragma unroll
      for (int e = 0; e < 8; e += 2){
        const float2 v = *(const float2*)&px[64 + e];
        agg[2][e]   = fmaf(v.x, ns, agg[2][e]);
        agg[2][e+1] = fmaf(v.y, ns, agg[2][e+1]);
      }
    } else if (kg == 1){
      const float2 v = *(const float2*)&px[72];
      agg[2][0] = fmaf(v.x, ns, agg[2][0]);
      agg[2][1] = fmaf(v.y, ns, agg[2][1]);
    }
  };

  int p0 = 0, p1 = 0;
  if (rok){ p0 = row_ptr[row]; p1 = row_ptr[row+1]; }
  int p = p0;
  #pragma unroll 1
  for (; p + 1 < p1; p += 2){
    const int sa = col[p], sb = col[p+1];
    const float na = norm_s[sa], nb = norm_s[sb];
    const float* xa = x0 + (size_t)sa*NODE_F;
    const float* xb = x0 + (size_t)sb*NODE_F;
    accum(xa, na);
    accum(xb, nb);
  }
  if (p < p1){
    const int sa = col[p];
    accum(x0 + (size_t)sa*NODE_F, norm_s[sa]);
  }

  const float nd = rok ? norm_d[row] : 0.f;
  bf16x8 ag[3], ar[3];
  #pragma unroll
  for (int s = 0; s < 3; ++s)
    #pragma unroll
    for (int e = 0; e < 8; ++e) ag[s][e] = (__bf16)(agg[s][e]*nd);

  {
    const int rA = rok ? row : (n-1);
    const float* px = x0 + (size_t)rA*NODE_F;
    #pragma unroll
    for (int s = 0; s < 2; ++s)
      #pragma unroll
      for (int e = 0; e < 8; e += 2){
        const float2 w = *(const float2*)&px[s*32 + kb + e];
        ar[s][e]   = (__bf16)w.x;
        ar[s][e+1] = (__bf16)w.y;
      }
    #pragma unroll
    for (int e = 0; e < 8; ++e) ar[2][e] = (__bf16)0.f;
    if (kg == 0){
      #pragma unroll
      for (int e = 0; e < 8; e += 2){
        const float2 w = *(const float2*)&px[64 + e];
        ar[2][e]   = (__bf16)w.x;
        ar[2][e+1] = (__bf16)w.y;
      }
    } else if (kg == 1){
      const float2 w = *(const float2*)&px[72];
      ar[2][0] = (__bf16)w.x;
      ar[2][1] = (__bf16)w.y;
    }
  }

  f32x4 accg[8], accr[8];
  #pragma unroll
  for (int t = 0; t < 8; ++t){
    accg[t] = f32x4{0.f,0.f,0.f,0.f};
    accr[t] = f32x4{0.f,0.f,0.f,0.f};
  }
  constexpr int FR1 = 8*3*512;
  #pragma unroll
  for (int s = 0; s < 3; ++s){
    #pragma unroll
    for (int t = 0; t < 8; ++t){
      const bf16x8 bg = __builtin_bit_cast(bf16x8,
          *(const s16x8*)&Bp[((t*3 + s)*64 + lane)*8]);
      const bf16x8 br = __builtin_bit_cast(bf16x8,
          *(const s16x8*)&Bp[FR1 + ((t*3 + s)*64 + lane)*8]);
      accg[t] = __builtin_amdgcn_mfma_f32_16x16x32_bf16(ag[s], bg, accg[t], 0,0,0);
      accr[t] = __builtin_amdgcn_mfma_f32_16x16x32_bf16(ar[s], br, accr[t], 0,0,0);
    }
  }

  const int rowb = r0 + 4*kg;
  #pragma unroll
  for (int t = 0; t < 8; ++t){
    const int colc = t*16 + jg;
    const float bgv = bg_[colc], brv = br_[colc];
    #pragma unroll
    for (int r = 0; r < 4; ++r){
      const int row2 = rowb + r;
      if (row2 < n){
        const float o = fmaxf(accg[t][r] + bgv, 0.f) + fmaxf(accr[t][r] + brv, 0.f);
        h1[(size_t)row2*HID + colc] = bfbits(o);
      }
    }
  }
}

// ---------------- fused layer 2 + readout: gather(h1) -> dual MFMA ->
// per-wave graph-reduced atomics into hsum/hmax (gid sorted ascending)
__global__ __launch_bounds__(256) void k_fgemm2(
    const u16* __restrict__ h1, const int* __restrict__ row_ptr,
    const int* __restrict__ col, const float* __restrict__ norm_s,
    const float* __restrict__ norm_d,
    const u16* __restrict__ Bp, const float* __restrict__ bg_,
    const float* __restrict__ br_,
    const float* __restrict__ w_atom, const float* __restrict__ b_atom,
    const int* __restrict__ gid,
    float* __restrict__ hsum, u32* __restrict__ hmax, int n){
  const int lane = threadIdx.x & 63;
  const int wid  = threadIdx.x >> 6;
  const int jg = lane & 15, kg = lane >> 4;
  const int r0 = blockIdx.x*64 + wid*16;
  const int row = r0 + jg;
  const bool rok = row < n;
  const int kb = kg*8;

  float agg[4][8];
  #pragma unroll
  for (int s = 0; s < 4; ++s)
    #pragma unroll
    for (int e = 0; e < 8; ++e) agg[s][e] = 0.f;

  auto accum = [&](uint4 v, int s, float ns){
    const float2 f0 = bfpair(v.x), f1 = bfpair(v.y);
    const float2 f2 = bfpair(v.z), f3 = bfpair(v.w);
    agg[s][0] = fmaf(f0.x, ns, agg[s][0]);
    agg[s][1] = fmaf(f0.y, ns, agg[s][1]);
    agg[s][2] = fmaf(f1.x, ns, agg[s][2]);
    agg[s][3] = fmaf(f1.y, ns, agg[s][3]);
    agg[s][4] = fmaf(f2.x, ns, agg[s][4]);
    agg[s][5] = fmaf(f2.y, ns, agg[s][5]);
    agg[s][6] = fmaf(f3.x, ns, agg[s][6]);
    agg[s][7] = fmaf(f3.y, ns, agg[s][7]);
  };

  int p0 = 0, p1 = 0;
  if (rok){ p0 = row_ptr[row]; p1 = row_ptr[row+1]; }
  int p = p0;
  #pragma unroll 1
  for (; p + 1 < p1; p += 2){
    const int sa = col[p], sb = col[p+1];
    const float na = norm_s[sa], nb = norm_s[sb];
    const u16* pa = h1 + (size_t)sa*HID + kb;
    const u16* pb = h1 + (size_t)sb*HID + kb;
    const uint4 va0 = *(const uint4*)(pa);
    const uint4 va1 = *(const uint4*)(pa + 32);
    const uint4 va2 = *(const uint4*)(pa + 64);
    const uint4 va3 = *(const uint4*)(pa + 96);
    const uint4 vb0 = *(const uint4*)(pb);
    const uint4 vb1 = *(const uint4*)(pb + 32);
    const uint4 vb2 = *(const uint4*)(pb + 64);
    const uint4 vb3 = *(const uint4*)(pb + 96);
    accum(va0, 0, na); accum(va1, 1, na); accum(va2, 2, na); accum(va3, 3, na);
    accum(vb0, 0, nb); accum(vb1, 1, nb); accum(vb2, 2, nb); accum(vb3, 3, nb);
  }
  if (p < p1){
    const int sa = col[p];
    const float na = norm_s[sa];
    const u16* pa = h1 + (size_t)sa*HID + kb;
    accum(*(const uint4*)(pa),      0, na);
    accum(*(const uint4*)(pa + 32), 1, na);
    accum(*(const uint4*)(pa + 64), 2, na);
    accum(*(const uint4*)(pa + 96), 3, na);
  }

  const float nd = rok ? norm_d[row] : 0.f;
  bf16x8 ag[4];
  #pragma unroll
  for (int s = 0; s < 4; ++s)
    #pragma unroll
    for (int e = 0; e < 8; ++e) ag[s][e] = (__bf16)(agg[s][e]*nd);

  const int rA = rok ? row : (n-1);
  const u16* phr = h1 + (size_t)rA*HID + kb;

  f32x4 accg[8], accr[8];
  #pragma unroll
  for (int t = 0; t < 8; ++t){
    accg[t] = f32x4{0.f,0.f,0.f,0.f};
    accr[t] = f32x4{0.f,0.f,0.f,0.f};
  }
  constexpr int FR2 = 8*4*512;
  #pragma unroll
  for (int s = 0; s < 4; ++s){
    const bf16x8 arf = __builtin_bit_cast(bf16x8, *(const s16x8*)(phr + s*32));
    #pragma unroll
    for (int t = 0; t < 8; ++t){
      const bf16x8 bg = __builtin_bit_cast(bf16x8,
          *(const s16x8*)&Bp[((t*4 + s)*64 + lane)*8]);
      const bf16x8 br = __builtin_bit_cast(bf16x8,
          *(const s16x8*)&Bp[FR2 + ((t*4 + s)*64 + lane)*8]);
      accg[t] = __builtin_amdgcn_mfma_f32_16x16x32_bf16(ag[s], bg, accg[t], 0,0,0);
      accr[t] = __builtin_amdgcn_mfma_f32_16x16x32_bf16(arf, br, accr[t], 0,0,0);
    }
  }

  // epilogue: h2 in registers -> fused WeightedSumAndMax readout.
  // Per-wave graph-aware reduction first (wave covers 16 consecutive rows,
  // sorted gid => 1-2 distinct graphs), then 1 atomic per (graph,col) per wave.
  float o[8][4];
  #pragma unroll
  for (int t = 0; t < 8; ++t){
    const int colc = t*16 + jg;
    const float bgv = bg_[colc], brv = br_[colc];
    #pragma unroll
    for (int r = 0; r < 4; ++r)
      o[t][r] = fmaxf(accg[t][r] + bgv, 0.f) + fmaxf(accr[t][r] + brv, 0.f);
  }
  if (r0 < n){
    float wa[8];
    #pragma unroll
    for (int t = 0; t < 8; ++t) wa[t] = w_atom[t*16 + jg];
    const float ba = b_atom[0];
    const int rowb = r0 + 4*kg;
    float awv[4]; int gidr[4];
    #pragma unroll
    for (int r = 0; r < 4; ++r){
      const int row2 = rowb + r;
      float dot = 0.f;
      #pragma unroll
      for (int t = 0; t < 8; ++t) dot = fmaf(o[t][r], wa[t], dot);
      dot += __shfl_xor(dot, 1);
      dot += __shfl_xor(dot, 2);
      dot += __shfl_xor(dot, 4);
      dot += __shfl_xor(dot, 8);
      awv[r]  = 1.0f/(1.0f + __expf(-(dot + ba)));
      gidr[r] = (row2 < n) ? gid[row2] : -1;
    }
    const int rhi    = (r0 + 15 < n) ? (r0 + 15) : (n - 1);
    const int gfirst = gid[r0];
    const int glast  = gid[rhi];
    for (int g = gfirst; g <= glast; ++g){
      #pragma unroll
      for (int t = 0; t < 8; ++t){
        float sv = 0.f, mv = 0.f;
        #pragma unroll
        for (int r = 0; r < 4; ++r){
          const bool in = (gidr[r] == g);
          sv += in ? o[t][r]*awv[r] : 0.f;
          mv  = in ? fmaxf(mv, o[t][r]) : mv;
        }
        sv += __shfl_xor(sv, 16);
        sv += __shfl_xor(sv, 32);
        mv  = fmaxf(mv, __shfl_xor(mv, 16));
        mv  = fmaxf(mv, __shfl_xor(mv, 32));
        if (lane < 16){
          atomicAdd(&hsum[(size_t)g*HID + t*16 + jg], sv);
          atomicMax(&hmax[(size_t)g*HID + t*16 + jg], __float_as_uint(mv));  // o >= 0
        }
      }
    }
  }
}

// ---------------- MLP layer 1: hid = relu(concat(hsum,hmax) @ Wp1 + bp1) ----------------
__global__ __launch_bounds__(256) void k_mlp1(
    const float* __restrict__ hsum, const float* __restrict__ hmaxf,
    const float* __restrict__ Wp1, const float* __restrict__ bp1,
    float* __restrict__ hid, int G_){
  const int lane = threadIdx.x & 63;
  const int row = blockIdx.x*4 + (threadIdx.x >> 6);
  if (row >= G_) return;
  const int c = lane*2;
  float ra0 = hsum[(size_t)row*HID + lane];
  float ra1 = hsum[(size_t)row*HID + 64 + lane];
  float ra2 = hmaxf[(size_t)row*HID + lane];
  float ra3 = hmaxf[(size_t)row*HID + 64 + lane];
  float a0 = 0.f, a1 = 0.f;
  #pragma unroll 4
  for (int k = 0; k < 64; ++k){
    const float v0 = rdl(ra0,k), v1 = rdl(ra1,k), v2 = rdl(ra2,k), v3 = rdl(ra3,k);
    const float2 w0 = *(const float2*)&Wp1[(size_t)(k      )*HID + c];
    const float2 w1 = *(const float2*)&Wp1[(size_t)(k +  64)*HID + c];
    const float2 w2 = *(const float2*)&Wp1[(size_t)(k + 128)*HID + c];
    const float2 w3 = *(const float2*)&Wp1[(size_t)(k + 192)*HID + c];
    a0 = fmaf(v0,w0.x, fmaf(v1,w1.x, fmaf(v2,w2.x, fmaf(v3,w3.x, a0))));
    a1 = fmaf(v0,w0.y, fmaf(v1,w1.y, fmaf(v2,w2.y, fmaf(v3,w3.y, a1))));
  }
  hid[(size_t)row*HID + c]   = fmaxf(a0 + bp1[c],   0.f);
  hid[(size_t)row*HID + c+1] = fmaxf(a1 + bp1[c+1], 0.f);
}

// ---------------- MLP layer 2 + zero-row insertion ----------------
__global__ __launch_bounds__(256) void k_mlp2(
    const float* __restrict__ hid, const float* __restrict__ Wp2,
    const float* __restrict__ bp2, const int* __restrict__ idxw, int K_,
    float* __restrict__ out, int G_){
  const int lane = threadIdx.x & 63;
  const int row = blockIdx.x*4 + (threadIdx.x >> 6);
  if (row >= G_) return;
  const int c = lane*4;
  float ra0 = hid[(size_t)row*HID + lane];
  float ra1 = hid[(size_t)row*HID + 64 + lane];
  float acc0=0.f, acc1=0.f, acc2=0.f, acc3=0.f;
  #pragma unroll 4
  for (int k = 0; k < 64; ++k){
    const float a = rdl(ra0, k);
    const float4 w = *(const float4*)&Wp2[(size_t)k*DIM + c];
    acc0 = fmaf(a,w.x,acc0); acc1 = fmaf(a,w.y,acc1);
    acc2 = fmaf(a,w.z,acc2); acc3 = fmaf(a,w.w,acc3);
  }
  #pragma unroll 4
  for (int k = 64; k < 128; ++k){
    const float a = rdl(ra1, k-64);
    const float4 w = *(const float4*)&Wp2[(size_t)k*DIM + c];
    acc0 = fmaf(a,w.x,acc0); acc1 = fmaf(a,w.y,acc1);
    acc2 = fmaf(a,w.z,acc2); acc3 = fmaf(a,w.w,acc3);
  }
  int orow = row;
  for (int j = 0; j < K_; ++j){ if (idxw[j] <= orow) orow++; }
  float* po = out + (size_t)orow*DIM + c;
  po[0] = acc0 + bp2[c];
  po[1] = acc1 + bp2[c+1];
  po[2] = acc2 + bp2[c+2];
  po[3] = acc3 + bp2[c+3];
}

extern "C" void kernel_launch(void* const* d_in, const int* in_sizes, int n_in,
                              void* d_out, int out_size, void* d_ws, size_t ws_size,
                              hipStream_t stream){
  (void)n_in; (void)ws_size;
  const float* x0     = (const float*)d_in[0];
  // d_in[1] = edge_feats (unused by the reference GCN)
  const float* W1     = (const float*)d_in[2];
  const float* b1     = (const float*)d_in[3];
  const float* Wr1    = (const float*)d_in[4];
  const float* br1    = (const float*)d_in[5];
  const float* W2     = (const float*)d_in[6];
  const float* b2     = (const float*)d_in[7];
  const float* Wr2    = (const float*)d_in[8];
  const float* br2    = (const float*)d_in[9];
  const float* w_atom = (const float*)d_in[10];
  const float* b_atom = (const float*)d_in[11];
  const float* Wp1    = (const float*)d_in[12];
  const float* bp1    = (const float*)d_in[13];
  const float* Wp2    = (const float*)d_in[14];
  const float* bp2    = (const float*)d_in[15];
  const int* src  = (const int*)d_in[16];
  const int* dst  = (const int*)d_in[17];
  const int* gid  = (const int*)d_in[18];
  const int* idxw = (const int*)d_in[19];

  const int N_ = in_sizes[0] / NODE_F;
  const int E_ = in_sizes[16];
  const int K_ = in_sizes[19];
  const int G_ = out_size / DIM - K_;

  // workspace (~32.6 MB — identical footprint to the proven baseline):
  //  [h1 bf16 N*128][norm_s N][norm_d N][hsum G*128][hmax G*128][hid G*128]
  //  [indeg N][row_ptr N+1 pad][col E]
  u16*   h1     = (u16*)d_ws;                          // N*128 u16
  float* norm_s = (float*)(h1 + (size_t)N_*HID);
  float* norm_d = norm_s + N_;
  float* hsum   = norm_d + N_;
  float* hmaxv  = hsum + (size_t)G_*HID;
  float* hid    = hmaxv + (size_t)G_*HID;
  int*   indeg  = (int*)(hid + (size_t)G_*HID);
  int*   row_ptr= indeg + N_;
  int*   col    = row_ptr + ((N_ + 4) & ~3);
  // weight-fragment scratch lives in d_out (2.56 MB total, frags = 112 KB);
  // d_out is memset AFTER k_fgemm2, before k_mlp2 writes it.
  u16*   Bp1    = (u16*)d_out;                         // 2*12288 u16
  u16*   Bp2    = Bp1 + 2*8*3*512;                     // 2*16384 u16

  hipMemsetAsync(norm_s, 0, (size_t)2*N_*sizeof(float), stream);
  hipMemsetAsync(hsum, 0, (size_t)2*G_*HID*sizeof(float), stream);
  hipMemsetAsync(indeg, 0, (size_t)N_*sizeof(int), stream);

  k_deg   <<<(E_+255)/256, 256, 0, stream>>>(src, dst, norm_s, indeg, E_);
  k_norm  <<<(N_+255)/256, 256, 0, stream>>>(norm_s, indeg, norm_d, N_);
  k_scan  <<<1, 1024, 0, stream>>>(indeg, row_ptr, N_);
  k_fill  <<<(E_+255)/256, 256, 0, stream>>>(src, dst, row_ptr, indeg, col, E_);

  k_prep<<<(8*3*512+255)/256, 256, 0, stream>>>(W1,  Bp1,            3, NODE_F);
  k_prep<<<(8*3*512+255)/256, 256, 0, stream>>>(Wr1, Bp1 + 8*3*512,  3, NODE_F);
  k_prep<<<(8*4*512+255)/256, 256, 0, stream>>>(W2,  Bp2,            4, HID);
  k_prep<<<(8*4*512+255)/256, 256, 0, stream>>>(Wr2, Bp2 + 8*4*512,  4, HID);

  const int nb = (N_ + 63) / 64;
  k_fgemm1<<<nb, 256, 0, stream>>>(x0, row_ptr, col, norm_s, norm_d,
                                   Bp1, b1, br1, h1, N_);
  k_fgemm2<<<nb, 256, 0, stream>>>(h1, row_ptr, col, norm_s, norm_d,
                                   Bp2, b2, br2, w_atom, b_atom, gid,
                                   hsum, (u32*)hmaxv, N_);

  // now safe to zero the output (weight frags no longer needed)
  hipMemsetAsync(d_out, 0, (size_t)out_size*sizeof(float), stream);

  k_mlp1<<<(G_+3)/4, 256, 0, stream>>>(hsum, hmaxv, Wp1, bp1, hid, G_);
  k_mlp2<<<(G_+3)/4, 256, 0, stream>>>(hid, Wp2, bp2, idxw, K_, (float*)d_out, G_);
}

// Round 4
// 367.677 us; speedup vs baseline: 2.7725x; 1.5884x over previous
//
#include <hip/hip_runtime.h>
#include <hip/hip_bf16.h>

#define NODE_F 74
#define HID 128
#define DIM 256

typedef __hip_bfloat16 bf16;
typedef unsigned int u32;
typedef unsigned short u16;

typedef short s16x8 __attribute__((ext_vector_type(8)));
typedef __bf16 bf16x8 __attribute__((ext_vector_type(8)));
typedef float f32x4 __attribute__((ext_vector_type(4)));

__device__ __forceinline__ float rdl(float v, int l){
  return __int_as_float(__builtin_amdgcn_readlane(__float_as_int(v), l));
}
__device__ __forceinline__ float2 bfpair(u32 u){
  float2 r;
  r.x = __uint_as_float(u << 16);
  r.y = __uint_as_float(u & 0xffff0000u);
  return r;
}
__device__ __forceinline__ u16 bfbits(float a){
  return __bfloat16_as_ushort(__float2bfloat16(a));
}

// ---------------- degrees ----------------
__global__ void k_deg(const int* __restrict__ src, const int* __restrict__ dst,
                      float* __restrict__ outdeg_f, int* __restrict__ indeg, int E_){
  int e = blockIdx.x*256 + threadIdx.x;
  if (e < E_){
    atomicAdd(&outdeg_f[src[e]], 1.0f);
    atomicAdd(&indeg[dst[e]], 1);
  }
}

__global__ void k_norm(float* __restrict__ norm_s, const int* __restrict__ indeg,
                       float* __restrict__ norm_d, int n){
  int i = blockIdx.x*256 + threadIdx.x;
  if (i < n){
    norm_s[i] = rsqrtf(fmaxf(norm_s[i], 1.0f));
    norm_d[i] = rsqrtf(fmaxf((float)indeg[i], 1.0f));
  }
}

// ---------------- CSR build: 3-phase device-wide exclusive scan ----------------
// phase a: per-block (1024 elems) reduce -> bsum[block]
__global__ __launch_bounds__(256) void k_scan_a(const int* __restrict__ indeg,
                                                int* __restrict__ bsum, int n){
  __shared__ int red[256];
  const int base = blockIdx.x*1024 + threadIdx.x*4;
  int s = 0;
  #pragma unroll
  for (int i = 0; i < 4; ++i){
    const int idx = base + i;
    s += (idx < n) ? indeg[idx] : 0;
  }
  red[threadIdx.x] = s;
  __syncthreads();
  #pragma unroll
  for (int off = 128; off; off >>= 1){
    if (threadIdx.x < off) red[threadIdx.x] += red[threadIdx.x + off];
    __syncthreads();
  }
  if (threadIdx.x == 0) bsum[blockIdx.x] = red[0];
}

// phase b: single block exclusive-scans bsum[nb] (handles nb > 1024 via chunks)
__global__ __launch_bounds__(1024) void k_scan_b(int* __restrict__ bsum, int nb){
  __shared__ int part[1024];
  __shared__ int carry;
  if (threadIdx.x == 0) carry = 0;
  __syncthreads();
  for (int c0 = 0; c0 < nb; c0 += 1024){
    const int tid = threadIdx.x, idx = c0 + tid;
    part[tid] = (idx < nb) ? bsum[idx] : 0;
    __syncthreads();
    for (int off = 1; off < 1024; off <<= 1){
      const int t = (tid >= off) ? part[tid-off] : 0;
      __syncthreads();
      part[tid] += t;
      __syncthreads();
    }
    if (idx < nb) bsum[idx] = carry + ((tid == 0) ? 0 : part[tid-1]);
    __syncthreads();
    if (tid == 0) carry += part[1023];
    __syncthreads();
  }
}

// phase c: per-block intra-scan + block offset -> row_ptr; zero indeg (cursor)
__global__ __launch_bounds__(256) void k_scan_c(int* __restrict__ indeg,
                                                const int* __restrict__ bsum,
                                                int* __restrict__ row_ptr, int n){
  __shared__ int part[256];
  const int base = blockIdx.x*1024 + threadIdx.x*4;
  int v[4]; int s = 0;
  #pragma unroll
  for (int i = 0; i < 4; ++i){
    const int idx = base + i;
    v[i] = (idx < n) ? indeg[idx] : 0;
    s += v[i];
  }
  part[threadIdx.x] = s;
  __syncthreads();
  for (int off = 1; off < 256; off <<= 1){
    const int t = (threadIdx.x >= off) ? part[threadIdx.x-off] : 0;
    __syncthreads();
    part[threadIdx.x] += t;
    __syncthreads();
  }
  int run = bsum[blockIdx.x] + ((threadIdx.x == 0) ? 0 : part[threadIdx.x-1]);
  #pragma unroll
  for (int i = 0; i < 4; ++i){
    const int idx = base + i;
    if (idx < n){
      row_ptr[idx] = run;
      run += v[i];
      indeg[idx] = 0;
    }
    if (idx == n-1) row_ptr[n] = run;
  }
}

__global__ void k_fill(const int* __restrict__ src, const int* __restrict__ dst,
                       const int* __restrict__ row_ptr, int* __restrict__ cursor,
                       int* __restrict__ col, int E_){
  int e = blockIdx.x*256 + threadIdx.x;
  if (e < E_){
    int d = dst[e];
    int pos = row_ptr[d] + atomicAdd(&cursor[d], 1);
    col[pos] = src[e];
  }
}

// ---------------- weight prepack: fp32 [K x 128] -> bf16 MFMA fragment order
// dst[((t*S + s)*64 + lane)*8 + e] = W[s*32 + (lane>>4)*8 + e][t*16 + (lane&15)]
__global__ void k_prep(const float* __restrict__ W, u16* __restrict__ dst,
                       int S, int Ktrue){
  int idx = blockIdx.x*256 + threadIdx.x;
  const int tot = 8*S*512;
  if (idx >= tot) return;
  const int e   = idx & 7;
  const int l   = (idx >> 3) & 63;
  const int rem = idx >> 9;
  const int s   = rem % S;
  const int t   = rem / S;
  const int k   = s*32 + (l >> 4)*8 + e;
  const int c   = t*16 + (l & 15);
  const float v = (k < Ktrue) ? W[(size_t)k*HID + c] : 0.f;
  dst[idx] = bfbits(v);
}

// ---------------- fused layer 1: gather(x0) -> dual MFMA -> h1 (bf16) ----------------
// Wave tile: rows r0..r0+15. Lane (jg,kg) gathers A[r0+jg][k], k = s*32+kg*8+e (K=96 pad).
// D: col = t*16 + jg, row = r0 + 4*kg + r.
__global__ __launch_bounds__(256) void k_fgemm1(
    const float* __restrict__ x0, const int* __restrict__ row_ptr,
    const int* __restrict__ col, const float* __restrict__ norm_s,
    const float* __restrict__ norm_d,
    const u16* __restrict__ Bp, const float* __restrict__ bg_,
    const float* __restrict__ br_, u16* __restrict__ h1, int n){
  const int lane = threadIdx.x & 63;
  const int wid  = threadIdx.x >> 6;
  const int jg = lane & 15, kg = lane >> 4;
  const int r0 = blockIdx.x*64 + wid*16;
  const int row = r0 + jg;
  const bool rok = row < n;
  const int kb = kg*8;

  float agg[3][8];
  #pragma unroll
  for (int s = 0; s < 3; ++s)
    #pragma unroll
    for (int e = 0; e < 8; ++e) agg[s][e] = 0.f;

  auto accum = [&](const float* px, float ns){
    #pragma unroll
    for (int s = 0; s < 2; ++s){
      #pragma unroll
      for (int e = 0; e < 8; e += 2){
        const float2 v = *(const float2*)&px[s*32 + kb + e];
        agg[s][e]   = fmaf(v.x, ns, agg[s][e]);
        agg[s][e+1] = fmaf(v.y, ns, agg[s][e+1]);
      }
    }
    if (kg == 0){
      #pragma unroll
      for (int e = 0; e < 8; e += 2){
        const float2 v = *(const float2*)&px[64 + e];
        agg[2][e]   = fmaf(v.x, ns, agg[2][e]);
        agg[2][e+1] = fmaf(v.y, ns, agg[2][e+1]);
      }
    } else if (kg == 1){
      const float2 v = *(const float2*)&px[72];
      agg[2][0] = fmaf(v.x, ns, agg[2][0]);
      agg[2][1] = fmaf(v.y, ns, agg[2][1]);
    }
  };

  int p0 = 0, p1 = 0;
  if (rok){ p0 = row_ptr[row]; p1 = row_ptr[row+1]; }
  int p = p0;
  #pragma unroll 1
  for (; p + 1 < p1; p += 2){
    const int sa = col[p], sb = col[p+1];
    const float na = norm_s[sa], nb = norm_s[sb];
    const float* xa = x0 + (size_t)sa*NODE_F;
    const float* xb = x0 + (size_t)sb*NODE_F;
    accum(xa, na);
    accum(xb, nb);
  }
  if (p < p1){
    const int sa = col[p];
    accum(x0 + (size_t)sa*NODE_F, norm_s[sa]);
  }

  const float nd = rok ? norm_d[row] : 0.f;
  bf16x8 ag[3], ar[3];
  #pragma unroll
  for (int s = 0; s < 3; ++s)
    #pragma unroll
    for (int e = 0; e < 8; ++e) ag[s][e] = (__bf16)(agg[s][e]*nd);

  {
    const int rA = rok ? row : (n-1);
    const float* px = x0 + (size_t)rA*NODE_F;
    #pragma unroll
    for (int s = 0; s < 2; ++s)
      #pragma unroll
      for (int e = 0; e < 8; e += 2){
        const float2 w = *(const float2*)&px[s*32 + kb + e];
        ar[s][e]   = (__bf16)w.x;
        ar[s][e+1] = (__bf16)w.y;
      }
    #pragma unroll
    for (int e = 0; e < 8; ++e) ar[2][e] = (__bf16)0.f;
    if (kg == 0){
      #pragma unroll
      for (int e = 0; e < 8; e += 2){
        const float2 w = *(const float2*)&px[64 + e];
        ar[2][e]   = (__bf16)w.x;
        ar[2][e+1] = (__bf16)w.y;
      }
    } else if (kg == 1){
      const float2 w = *(const float2*)&px[72];
      ar[2][0] = (__bf16)w.x;
      ar[2][1] = (__bf16)w.y;
    }
  }

  f32x4 accg[8], accr[8];
  #pragma unroll
  for (int t = 0; t < 8; ++t){
    accg[t] = f32x4{0.f,0.f,0.f,0.f};
    accr[t] = f32x4{0.f,0.f,0.f,0.f};
  }
  constexpr int FR1 = 8*3*512;
  #pragma unroll
  for (int s = 0; s < 3; ++s){
    #pragma unroll
    for (int t = 0; t < 8; ++t){
      const bf16x8 bg = __builtin_bit_cast(bf16x8,
          *(const s16x8*)&Bp[((t*3 + s)*64 + lane)*8]);
      const bf16x8 br = __builtin_bit_cast(bf16x8,
          *(const s16x8*)&Bp[FR1 + ((t*3 + s)*64 + lane)*8]);
      accg[t] = __builtin_amdgcn_mfma_f32_16x16x32_bf16(ag[s], bg, accg[t], 0,0,0);
      accr[t] = __builtin_amdgcn_mfma_f32_16x16x32_bf16(ar[s], br, accr[t], 0,0,0);
    }
  }

  const int rowb = r0 + 4*kg;
  #pragma unroll
  for (int t = 0; t < 8; ++t){
    const int colc = t*16 + jg;
    const float bgv = bg_[colc], brv = br_[colc];
    #pragma unroll
    for (int r = 0; r < 4; ++r){
      const int row2 = rowb + r;
      if (row2 < n){
        const float o = fmaxf(accg[t][r] + bgv, 0.f) + fmaxf(accr[t][r] + brv, 0.f);
        h1[(size_t)row2*HID + colc] = bfbits(o);
      }
    }
  }
}

// ---------------- fused layer 2 + readout: gather(h1) -> dual MFMA ->
// per-wave graph-reduced atomics into hsum/hmax (gid sorted ascending)
__global__ __launch_bounds__(256) void k_fgemm2(
    const u16* __restrict__ h1, const int* __restrict__ row_ptr,
    const int* __restrict__ col, const float* __restrict__ norm_s,
    const float* __restrict__ norm_d,
    const u16* __restrict__ Bp, const float* __restrict__ bg_,
    const float* __restrict__ br_,
    const float* __restrict__ w_atom, const float* __restrict__ b_atom,
    const int* __restrict__ gid,
    float* __restrict__ hsum, u32* __restrict__ hmax, int n){
  const int lane = threadIdx.x & 63;
  const int wid  = threadIdx.x >> 6;
  const int jg = lane & 15, kg = lane >> 4;
  const int r0 = blockIdx.x*64 + wid*16;
  const int row = r0 + jg;
  const bool rok = row < n;
  const int kb = kg*8;

  float agg[4][8];
  #pragma unroll
  for (int s = 0; s < 4; ++s)
    #pragma unroll
    for (int e = 0; e < 8; ++e) agg[s][e] = 0.f;

  auto accum = [&](uint4 v, int s, float ns){
    const float2 f0 = bfpair(v.x), f1 = bfpair(v.y);
    const float2 f2 = bfpair(v.z), f3 = bfpair(v.w);
    agg[s][0] = fmaf(f0.x, ns, agg[s][0]);
    agg[s][1] = fmaf(f0.y, ns, agg[s][1]);
    agg[s][2] = fmaf(f1.x, ns, agg[s][2]);
    agg[s][3] = fmaf(f1.y, ns, agg[s][3]);
    agg[s][4] = fmaf(f2.x, ns, agg[s][4]);
    agg[s][5] = fmaf(f2.y, ns, agg[s][5]);
    agg[s][6] = fmaf(f3.x, ns, agg[s][6]);
    agg[s][7] = fmaf(f3.y, ns, agg[s][7]);
  };

  int p0 = 0, p1 = 0;
  if (rok){ p0 = row_ptr[row]; p1 = row_ptr[row+1]; }
  int p = p0;
  #pragma unroll 1
  for (; p + 1 < p1; p += 2){
    const int sa = col[p], sb = col[p+1];
    const float na = norm_s[sa], nb = norm_s[sb];
    const u16* pa = h1 + (size_t)sa*HID + kb;
    const u16* pb = h1 + (size_t)sb*HID + kb;
    const uint4 va0 = *(const uint4*)(pa);
    const uint4 va1 = *(const uint4*)(pa + 32);
    const uint4 va2 = *(const uint4*)(pa + 64);
    const uint4 va3 = *(const uint4*)(pa + 96);
    const uint4 vb0 = *(const uint4*)(pb);
    const uint4 vb1 = *(const uint4*)(pb + 32);
    const uint4 vb2 = *(const uint4*)(pb + 64);
    const uint4 vb3 = *(const uint4*)(pb + 96);
    accum(va0, 0, na); accum(va1, 1, na); accum(va2, 2, na); accum(va3, 3, na);
    accum(vb0, 0, nb); accum(vb1, 1, nb); accum(vb2, 2, nb); accum(vb3, 3, nb);
  }
  if (p < p1){
    const int sa = col[p];
    const float na = norm_s[sa];
    const u16* pa = h1 + (size_t)sa*HID + kb;
    accum(*(const uint4*)(pa),      0, na);
    accum(*(const uint4*)(pa + 32), 1, na);
    accum(*(const uint4*)(pa + 64), 2, na);
    accum(*(const uint4*)(pa + 96), 3, na);
  }

  const float nd = rok ? norm_d[row] : 0.f;
  bf16x8 ag[4];
  #pragma unroll
  for (int s = 0; s < 4; ++s)
    #pragma unroll
    for (int e = 0; e < 8; ++e) ag[s][e] = (__bf16)(agg[s][e]*nd);

  const int rA = rok ? row : (n-1);
  const u16* phr = h1 + (size_t)rA*HID + kb;

  f32x4 accg[8], accr[8];
  #pragma unroll
  for (int t = 0; t < 8; ++t){
    accg[t] = f32x4{0.f,0.f,0.f,0.f};
    accr[t] = f32x4{0.f,0.f,0.f,0.f};
  }
  constexpr int FR2 = 8*4*512;
  #pragma unroll
  for (int s = 0; s < 4; ++s){
    const bf16x8 arf = __builtin_bit_cast(bf16x8, *(const s16x8*)(phr + s*32));
    #pragma unroll
    for (int t = 0; t < 8; ++t){
      const bf16x8 bg = __builtin_bit_cast(bf16x8,
          *(const s16x8*)&Bp[((t*4 + s)*64 + lane)*8]);
      const bf16x8 br = __builtin_bit_cast(bf16x8,
          *(const s16x8*)&Bp[FR2 + ((t*4 + s)*64 + lane)*8]);
      accg[t] = __builtin_amdgcn_mfma_f32_16x16x32_bf16(ag[s], bg, accg[t], 0,0,0);
      accr[t] = __builtin_amdgcn_mfma_f32_16x16x32_bf16(arf, br, accr[t], 0,0,0);
    }
  }

  // epilogue: h2 in registers -> fused WeightedSumAndMax readout.
  float o[8][4];
  #pragma unroll
  for (int t = 0; t < 8; ++t){
    const int colc = t*16 + jg;
    const float bgv = bg_[colc], brv = br_[colc];
    #pragma unroll
    for (int r = 0; r < 4; ++r)
      o[t][r] = fmaxf(accg[t][r] + bgv, 0.f) + fmaxf(accr[t][r] + brv, 0.f);
  }
  if (r0 < n){
    float wa[8];
    #pragma unroll
    for (int t = 0; t < 8; ++t) wa[t] = w_atom[t*16 + jg];
    const float ba = b_atom[0];
    const int rowb = r0 + 4*kg;
    float awv[4]; int gidr[4];
    #pragma unroll
    for (int r = 0; r < 4; ++r){
      const int row2 = rowb + r;
      float dot = 0.f;
      #pragma unroll
      for (int t = 0; t < 8; ++t) dot = fmaf(o[t][r], wa[t], dot);
      dot += __shfl_xor(dot, 1);
      dot += __shfl_xor(dot, 2);
      dot += __shfl_xor(dot, 4);
      dot += __shfl_xor(dot, 8);
      awv[r]  = 1.0f/(1.0f + __expf(-(dot + ba)));
      gidr[r] = (row2 < n) ? gid[row2] : -1;
    }
    const int rhi    = (r0 + 15 < n) ? (r0 + 15) : (n - 1);
    const int gfirst = gid[r0];
    const int glast  = gid[rhi];
    for (int g = gfirst; g <= glast; ++g){
      #pragma unroll
      for (int t = 0; t < 8; ++t){
        float sv = 0.f, mv = 0.f;
        #pragma unroll
        for (int r = 0; r < 4; ++r){
          const bool in = (gidr[r] == g);
          sv += in ? o[t][r]*awv[r] : 0.f;
          mv  = in ? fmaxf(mv, o[t][r]) : mv;
        }
        sv += __shfl_xor(sv, 16);
        sv += __shfl_xor(sv, 32);
        mv  = fmaxf(mv, __shfl_xor(mv, 16));
        mv  = fmaxf(mv, __shfl_xor(mv, 32));
        if (lane < 16){
          atomicAdd(&hsum[(size_t)g*HID + t*16 + jg], sv);
          atomicMax(&hmax[(size_t)g*HID + t*16 + jg], __float_as_uint(mv));  // o >= 0
        }
      }
    }
  }
}

// ---------------- MLP layer 1: hid = relu(concat(hsum,hmax) @ Wp1 + bp1) ----------------
__global__ __launch_bounds__(256) void k_mlp1(
    const float* __restrict__ hsum, const float* __restrict__ hmaxf,
    const float* __restrict__ Wp1, const float* __restrict__ bp1,
    float* __restrict__ hid, int G_){
  const int lane = threadIdx.x & 63;
  const int row = blockIdx.x*4 + (threadIdx.x >> 6);
  if (row >= G_) return;
  const int c = lane*2;
  float ra0 = hsum[(size_t)row*HID + lane];
  float ra1 = hsum[(size_t)row*HID + 64 + lane];
  float ra2 = hmaxf[(size_t)row*HID + lane];
  float ra3 = hmaxf[(size_t)row*HID + 64 + lane];
  float a0 = 0.f, a1 = 0.f;
  #pragma unroll 4
  for (int k = 0; k < 64; ++k){
    const float v0 = rdl(ra0,k), v1 = rdl(ra1,k), v2 = rdl(ra2,k), v3 = rdl(ra3,k);
    const float2 w0 = *(const float2*)&Wp1[(size_t)(k      )*HID + c];
    const float2 w1 = *(const float2*)&Wp1[(size_t)(k +  64)*HID + c];
    const float2 w2 = *(const float2*)&Wp1[(size_t)(k + 128)*HID + c];
    const float2 w3 = *(const float2*)&Wp1[(size_t)(k + 192)*HID + c];
    a0 = fmaf(v0,w0.x, fmaf(v1,w1.x, fmaf(v2,w2.x, fmaf(v3,w3.x, a0))));
    a1 = fmaf(v0,w0.y, fmaf(v1,w1.y, fmaf(v2,w2.y, fmaf(v3,w3.y, a1))));
  }
  hid[(size_t)row*HID + c]   = fmaxf(a0 + bp1[c],   0.f);
  hid[(size_t)row*HID + c+1] = fmaxf(a1 + bp1[c+1], 0.f);
}

// ---------------- MLP layer 2 + zero-row insertion ----------------
__global__ __launch_bounds__(256) void k_mlp2(
    const float* __restrict__ hid, const float* __restrict__ Wp2,
    const float* __restrict__ bp2, const int* __restrict__ idxw, int K_,
    float* __restrict__ out, int G_){
  const int lane = threadIdx.x & 63;
  const int row = blockIdx.x*4 + (threadIdx.x >> 6);
  if (row >= G_) return;
  const int c = lane*4;
  float ra0 = hid[(size_t)row*HID + lane];
  float ra1 = hid[(size_t)row*HID + 64 + lane];
  float acc0=0.f, acc1=0.f, acc2=0.f, acc3=0.f;
  #pragma unroll 4
  for (int k = 0; k < 64; ++k){
    const float a = rdl(ra0, k);
    const float4 w = *(const float4*)&Wp2[(size_t)k*DIM + c];
    acc0 = fmaf(a,w.x,acc0); acc1 = fmaf(a,w.y,acc1);
    acc2 = fmaf(a,w.z,acc2); acc3 = fmaf(a,w.w,acc3);
  }
  #pragma unroll 4
  for (int k = 64; k < 128; ++k){
    const float a = rdl(ra1, k-64);
    const float4 w = *(const float4*)&Wp2[(size_t)k*DIM + c];
    acc0 = fmaf(a,w.x,acc0); acc1 = fmaf(a,w.y,acc1);
    acc2 = fmaf(a,w.z,acc2); acc3 = fmaf(a,w.w,acc3);
  }
  int orow = row;
  for (int j = 0; j < K_; ++j){ if (idxw[j] <= orow) orow++; }
  float* po = out + (size_t)orow*DIM + c;
  po[0] = acc0 + bp2[c];
  po[1] = acc1 + bp2[c+1];
  po[2] = acc2 + bp2[c+2];
  po[3] = acc3 + bp2[c+3];
}

extern "C" void kernel_launch(void* const* d_in, const int* in_sizes, int n_in,
                              void* d_out, int out_size, void* d_ws, size_t ws_size,
                              hipStream_t stream){
  (void)n_in; (void)ws_size;
  const float* x0     = (const float*)d_in[0];
  // d_in[1] = edge_feats (unused by the reference GCN)
  const float* W1     = (const float*)d_in[2];
  const float* b1     = (const float*)d_in[3];
  const float* Wr1    = (const float*)d_in[4];
  const float* br1    = (const float*)d_in[5];
  const float* W2     = (const float*)d_in[6];
  const float* b2     = (const float*)d_in[7];
  const float* Wr2    = (const float*)d_in[8];
  const float* br2    = (const float*)d_in[9];
  const float* w_atom = (const float*)d_in[10];
  const float* b_atom = (const float*)d_in[11];
  const float* Wp1    = (const float*)d_in[12];
  const float* bp1    = (const float*)d_in[13];
  const float* Wp2    = (const float*)d_in[14];
  const float* bp2    = (const float*)d_in[15];
  const int* src  = (const int*)d_in[16];
  const int* dst  = (const int*)d_in[17];
  const int* gid  = (const int*)d_in[18];
  const int* idxw = (const int*)d_in[19];

  const int N_ = in_sizes[0] / NODE_F;
  const int E_ = in_sizes[16];
  const int K_ = in_sizes[19];
  const int G_ = out_size / DIM - K_;

  // workspace: [h1 bf16 N*128][norm_s N][norm_d N][hsum G*128][hmax G*128]
  //            [hid G*128][indeg N][row_ptr N+1 pad][col E][bsum nb]
  u16*   h1     = (u16*)d_ws;                          // N*128 u16
  float* norm_s = (float*)(h1 + (size_t)N_*HID);
  float* norm_d = norm_s + N_;
  float* hsum   = norm_d + N_;
  float* hmaxv  = hsum + (size_t)G_*HID;
  float* hid    = hmaxv + (size_t)G_*HID;
  int*   indeg  = (int*)(hid + (size_t)G_*HID);
  int*   row_ptr= indeg + N_;
  int*   col    = row_ptr + ((N_ + 4) & ~3);
  int*   bsum   = col + ((E_ + 4) & ~3);
  // weight-fragment scratch lives in d_out (2.56 MB total, frags = 112 KB);
  // d_out is memset AFTER k_fgemm2, before k_mlp2 writes it.
  u16*   Bp1    = (u16*)d_out;                         // 2*12288 u16
  u16*   Bp2    = Bp1 + 2*8*3*512;                     // 2*16384 u16

  hipMemsetAsync(norm_s, 0, (size_t)2*N_*sizeof(float), stream);
  hipMemsetAsync(hsum, 0, (size_t)2*G_*HID*sizeof(float), stream);
  hipMemsetAsync(indeg, 0, (size_t)N_*sizeof(int), stream);

  const int nscan = (N_ + 1023)/1024;
  k_deg   <<<(E_+255)/256, 256, 0, stream>>>(src, dst, norm_s, indeg, E_);
  k_norm  <<<(N_+255)/256, 256, 0, stream>>>(norm_s, indeg, norm_d, N_);
  k_scan_a<<<nscan, 256, 0, stream>>>(indeg, bsum, N_);
  k_scan_b<<<1, 1024, 0, stream>>>(bsum, nscan);
  k_scan_c<<<nscan, 256, 0, stream>>>(indeg, bsum, row_ptr, N_);
  k_fill  <<<(E_+255)/256, 256, 0, stream>>>(src, dst, row_ptr, indeg, col, E_);

  k_prep<<<(8*3*512+255)/256, 256, 0, stream>>>(W1,  Bp1,            3, NODE_F);
  k_prep<<<(8*3*512+255)/256, 256, 0, stream>>>(Wr1, Bp1 + 8*3*512,  3, NODE_F);
  k_prep<<<(8*4*512+255)/256, 256, 0, stream>>>(W2,  Bp2,            4, HID);
  k_prep<<<(8*4*512+255)/256, 256, 0, stream>>>(Wr2, Bp2 + 8*4*512,  4, HID);

  const int nb = (N_ + 63) / 64;
  k_fgemm1<<<nb, 256, 0, stream>>>(x0, row_ptr, col, norm_s, norm_d,
                                   Bp1, b1, br1, h1, N_);
  k_fgemm2<<<nb, 256, 0, stream>>>(h1, row_ptr, col, norm_s, norm_d,
                                   Bp2, b2, br2, w_atom, b_atom, gid,
                                   hsum, (u32*)hmaxv, N_);

  // now safe to zero the output (weight frags no longer needed)
  hipMemsetAsync(d_out, 0, (size_t)out_size*sizeof(float), stream);

  k_mlp1<<<(G_+3)/4, 256, 0, stream>>>(hsum, hmaxv, Wp1, bp1, hid, G_);
  k_mlp2<<<(G_+3)/4, 256, 0, stream>>>(hid, Wp2, bp2, idxw, K_, (float*)d_out, G_);
}

// Round 5
// 366.677 us; speedup vs baseline: 2.7801x; 1.0027x over previous
//
#include <hip/hip_runtime.h>
#include <hip/hip_bf16.h>

#define NODE_F 74
#define HID 128
#define DIM 256

typedef __hip_bfloat16 bf16;
typedef unsigned int u32;
typedef unsigned short u16;

typedef short s16x8 __attribute__((ext_vector_type(8)));
typedef __bf16 bf16x8 __attribute__((ext_vector_type(8)));
typedef float f32x4 __attribute__((ext_vector_type(4)));

__device__ __forceinline__ float rdl(float v, int l){
  return __int_as_float(__builtin_amdgcn_readlane(__float_as_int(v), l));
}
__device__ __forceinline__ float2 bfpair(u32 u){
  float2 r;
  r.x = __uint_as_float(u << 16);
  r.y = __uint_as_float(u & 0xffff0000u);
  return r;
}
__device__ __forceinline__ u16 bfbits(float a){
  return __bfloat16_as_ushort(__float2bfloat16(a));
}

// ---------------- degrees ----------------
__global__ void k_deg(const int* __restrict__ src, const int* __restrict__ dst,
                      float* __restrict__ outdeg_f, int* __restrict__ indeg, int E_){
  int e = blockIdx.x*256 + threadIdx.x;
  if (e < E_){
    atomicAdd(&outdeg_f[src[e]], 1.0f);
    atomicAdd(&indeg[dst[e]], 1);
  }
}

// ---------------- CSR build: 3-phase device-wide exclusive scan ----------------
// phase a: per-block (1024 elems) reduce -> bsum[block]; also finalizes norms
__global__ __launch_bounds__(256) void k_scan_a(const int* __restrict__ indeg,
                                                float* __restrict__ norm_s,
                                                float* __restrict__ norm_d,
                                                int* __restrict__ bsum, int n){
  __shared__ int red[256];
  const int base = blockIdx.x*1024 + threadIdx.x*4;
  int s = 0;
  #pragma unroll
  for (int i = 0; i < 4; ++i){
    const int idx = base + i;
    if (idx < n){
      const int d = indeg[idx];
      s += d;
      norm_d[idx] = rsqrtf(fmaxf((float)d, 1.0f));
      norm_s[idx] = rsqrtf(fmaxf(norm_s[idx], 1.0f));
    }
  }
  red[threadIdx.x] = s;
  __syncthreads();
  #pragma unroll
  for (int off = 128; off; off >>= 1){
    if (threadIdx.x < off) red[threadIdx.x] += red[threadIdx.x + off];
    __syncthreads();
  }
  if (threadIdx.x == 0) bsum[blockIdx.x] = red[0];
}

// phase b: single block exclusive-scans bsum[nb] (handles nb > 1024 via chunks)
__global__ __launch_bounds__(1024) void k_scan_b(int* __restrict__ bsum, int nb){
  __shared__ int part[1024];
  __shared__ int carry;
  if (threadIdx.x == 0) carry = 0;
  __syncthreads();
  for (int c0 = 0; c0 < nb; c0 += 1024){
    const int tid = threadIdx.x, idx = c0 + tid;
    part[tid] = (idx < nb) ? bsum[idx] : 0;
    __syncthreads();
    for (int off = 1; off < 1024; off <<= 1){
      const int t = (tid >= off) ? part[tid-off] : 0;
      __syncthreads();
      part[tid] += t;
      __syncthreads();
    }
    if (idx < nb) bsum[idx] = carry + ((tid == 0) ? 0 : part[tid-1]);
    __syncthreads();
    if (tid == 0) carry += part[1023];
    __syncthreads();
  }
}

// phase c: per-block intra-scan + block offset -> row_ptr; zero indeg (cursor)
__global__ __launch_bounds__(256) void k_scan_c(int* __restrict__ indeg,
                                                const int* __restrict__ bsum,
                                                int* __restrict__ row_ptr, int n){
  __shared__ int part[256];
  const int base = blockIdx.x*1024 + threadIdx.x*4;
  int v[4]; int s = 0;
  #pragma unroll
  for (int i = 0; i < 4; ++i){
    const int idx = base + i;
    v[i] = (idx < n) ? indeg[idx] : 0;
    s += v[i];
  }
  part[threadIdx.x] = s;
  __syncthreads();
  for (int off = 1; off < 256; off <<= 1){
    const int t = (threadIdx.x >= off) ? part[threadIdx.x-off] : 0;
    __syncthreads();
    part[threadIdx.x] += t;
    __syncthreads();
  }
  int run = bsum[blockIdx.x] + ((threadIdx.x == 0) ? 0 : part[threadIdx.x-1]);
  #pragma unroll
  for (int i = 0; i < 4; ++i){
    const int idx = base + i;
    if (idx < n){
      row_ptr[idx] = run;
      run += v[i];
      indeg[idx] = 0;
    }
    if (idx == n-1) row_ptr[n] = run;
  }
}

__global__ void k_fill(const int* __restrict__ src, const int* __restrict__ dst,
                       const int* __restrict__ row_ptr, int* __restrict__ cursor,
                       int* __restrict__ col, int E_){
  int e = blockIdx.x*256 + threadIdx.x;
  if (e < E_){
    int d = dst[e];
    int pos = row_ptr[d] + atomicAdd(&cursor[d], 1);
    col[pos] = src[e];
  }
}

// ---------------- weight prepack (all 4 matrices in one launch) ----------------
// dst[((t*S + s)*64 + lane)*8 + e] = W[s*32 + (lane>>4)*8 + e][t*16 + (lane&15)]
__global__ __launch_bounds__(256) void k_prep_all(
    const float* __restrict__ W1, const float* __restrict__ Wr1,
    const float* __restrict__ W2, const float* __restrict__ Wr2,
    u16* __restrict__ Bp1, u16* __restrict__ Bp2){
  int idx = blockIdx.x*256 + threadIdx.x;
  const float* W; u16* dst; int S, Ktrue, loc;
  if      (idx < 12288){ W = W1;  dst = Bp1;          S = 3; Ktrue = NODE_F; loc = idx; }
  else if (idx < 24576){ W = Wr1; dst = Bp1 + 12288;  S = 3; Ktrue = NODE_F; loc = idx - 12288; }
  else if (idx < 40960){ W = W2;  dst = Bp2;          S = 4; Ktrue = HID;    loc = idx - 24576; }
  else if (idx < 57344){ W = Wr2; dst = Bp2 + 16384;  S = 4; Ktrue = HID;    loc = idx - 40960; }
  else return;
  const int e   = loc & 7;
  const int l   = (loc >> 3) & 63;
  const int rem = loc >> 9;
  const int s   = rem % S;
  const int t   = rem / S;
  const int k   = s*32 + (l >> 4)*8 + e;
  const int c   = t*16 + (l & 15);
  const float v = (k < Ktrue) ? W[(size_t)k*HID + c] : 0.f;
  dst[loc] = bfbits(v);
}

// ---------------- fused layer 1: gather(x0) -> dual MFMA -> h1 (bf16) ----------------
// Wave tile: rows r0..r0+15. Lane (jg,kg) gathers A[r0+jg][k], k = s*32+kg*8+e (K=96 pad).
// D: col = t*16 + jg, row = r0 + 4*kg + r.
__global__ __launch_bounds__(256) void k_fgemm1(
    const float* __restrict__ x0, const int* __restrict__ row_ptr,
    const int* __restrict__ col, const float* __restrict__ norm_s,
    const float* __restrict__ norm_d,
    const u16* __restrict__ Bp, const float* __restrict__ bg_,
    const float* __restrict__ br_, u16* __restrict__ h1, int n){
  const int lane = threadIdx.x & 63;
  const int wid  = threadIdx.x >> 6;
  const int jg = lane & 15, kg = lane >> 4;
  const int r0 = blockIdx.x*64 + wid*16;
  const int row = r0 + jg;
  const bool rok = row < n;
  const int kb = kg*8;

  float agg[3][8];
  #pragma unroll
  for (int s = 0; s < 3; ++s)
    #pragma unroll
    for (int e = 0; e < 8; ++e) agg[s][e] = 0.f;

  auto accum = [&](const float* px, float ns){
    #pragma unroll
    for (int s = 0; s < 2; ++s){
      #pragma unroll
      for (int e = 0; e < 8; e += 2){
        const float2 v = *(const float2*)&px[s*32 + kb + e];
        agg[s][e]   = fmaf(v.x, ns, agg[s][e]);
        agg[s][e+1] = fmaf(v.y, ns, agg[s][e+1]);
      }
    }
    if (kg == 0){
      #pragma unroll
      for (int e = 0; e < 8; e += 2){
        const float2 v = *(const float2*)&px[64 + e];
        agg[2][e]   = fmaf(v.x, ns, agg[2][e]);
        agg[2][e+1] = fmaf(v.y, ns, agg[2][e+1]);
      }
    } else if (kg == 1){
      const float2 v = *(const float2*)&px[72];
      agg[2][0] = fmaf(v.x, ns, agg[2][0]);
      agg[2][1] = fmaf(v.y, ns, agg[2][1]);
    }
  };

  int p0 = 0, p1 = 0;
  if (rok){ p0 = row_ptr[row]; p1 = row_ptr[row+1]; }
  int p = p0;
  #pragma unroll 1
  for (; p + 3 < p1; p += 4){
    const int s0 = col[p], s1 = col[p+1], s2 = col[p+2], s3 = col[p+3];
    const float n0 = norm_s[s0], n1 = norm_s[s1], n2 = norm_s[s2], n3 = norm_s[s3];
    accum(x0 + (size_t)s0*NODE_F, n0);
    accum(x0 + (size_t)s1*NODE_F, n1);
    accum(x0 + (size_t)s2*NODE_F, n2);
    accum(x0 + (size_t)s3*NODE_F, n3);
  }
  #pragma unroll 1
  for (; p + 1 < p1; p += 2){
    const int s0 = col[p], s1 = col[p+1];
    const float n0 = norm_s[s0], n1 = norm_s[s1];
    accum(x0 + (size_t)s0*NODE_F, n0);
    accum(x0 + (size_t)s1*NODE_F, n1);
  }
  if (p < p1){
    const int s0 = col[p];
    accum(x0 + (size_t)s0*NODE_F, norm_s[s0]);
  }

  const float nd = rok ? norm_d[row] : 0.f;
  bf16x8 ag[3], ar[3];
  #pragma unroll
  for (int s = 0; s < 3; ++s)
    #pragma unroll
    for (int e = 0; e < 8; ++e) ag[s][e] = (__bf16)(agg[s][e]*nd);

  {
    const int rA = rok ? row : (n-1);
    const float* px = x0 + (size_t)rA*NODE_F;
    #pragma unroll
    for (int s = 0; s < 2; ++s)
      #pragma unroll
      for (int e = 0; e < 8; e += 2){
        const float2 w = *(const float2*)&px[s*32 + kb + e];
        ar[s][e]   = (__bf16)w.x;
        ar[s][e+1] = (__bf16)w.y;
      }
    #pragma unroll
    for (int e = 0; e < 8; ++e) ar[2][e] = (__bf16)0.f;
    if (kg == 0){
      #pragma unroll
      for (int e = 0; e < 8; e += 2){
        const float2 w = *(const float2*)&px[64 + e];
        ar[2][e]   = (__bf16)w.x;
        ar[2][e+1] = (__bf16)w.y;
      }
    } else if (kg == 1){
      const float2 w = *(const float2*)&px[72];
      ar[2][0] = (__bf16)w.x;
      ar[2][1] = (__bf16)w.y;
    }
  }

  f32x4 accg[8], accr[8];
  #pragma unroll
  for (int t = 0; t < 8; ++t){
    accg[t] = f32x4{0.f,0.f,0.f,0.f};
    accr[t] = f32x4{0.f,0.f,0.f,0.f};
  }
  constexpr int FR1 = 8*3*512;
  #pragma unroll
  for (int s = 0; s < 3; ++s){
    #pragma unroll
    for (int t = 0; t < 8; ++t){
      const bf16x8 bg = __builtin_bit_cast(bf16x8,
          *(const s16x8*)&Bp[((t*3 + s)*64 + lane)*8]);
      const bf16x8 br = __builtin_bit_cast(bf16x8,
          *(const s16x8*)&Bp[FR1 + ((t*3 + s)*64 + lane)*8]);
      accg[t] = __builtin_amdgcn_mfma_f32_16x16x32_bf16(ag[s], bg, accg[t], 0,0,0);
      accr[t] = __builtin_amdgcn_mfma_f32_16x16x32_bf16(ar[s], br, accr[t], 0,0,0);
    }
  }

  const int rowb = r0 + 4*kg;
  #pragma unroll
  for (int t = 0; t < 8; ++t){
    const int colc = t*16 + jg;
    const float bgv = bg_[colc], brv = br_[colc];
    #pragma unroll
    for (int r = 0; r < 4; ++r){
      const int row2 = rowb + r;
      if (row2 < n){
        const float o = fmaxf(accg[t][r] + bgv, 0.f) + fmaxf(accr[t][r] + brv, 0.f);
        h1[(size_t)row2*HID + colc] = bfbits(o);
      }
    }
  }
}

// ---------------- fused layer 2 + readout: gather(h1) -> dual MFMA ->
// per-wave graph-reduced atomics into hsum/hmax (gid sorted ascending)
__global__ __launch_bounds__(256) void k_fgemm2(
    const u16* __restrict__ h1, const int* __restrict__ row_ptr,
    const int* __restrict__ col, const float* __restrict__ norm_s,
    const float* __restrict__ norm_d,
    const u16* __restrict__ Bp, const float* __restrict__ bg_,
    const float* __restrict__ br_,
    const float* __restrict__ w_atom, const float* __restrict__ b_atom,
    const int* __restrict__ gid,
    float* __restrict__ hsum, u32* __restrict__ hmax, int n){
  const int lane = threadIdx.x & 63;
  const int wid  = threadIdx.x >> 6;
  const int jg = lane & 15, kg = lane >> 4;
  const int r0 = blockIdx.x*64 + wid*16;
  const int row = r0 + jg;
  const bool rok = row < n;
  const int kb = kg*8;

  float agg[4][8];
  #pragma unroll
  for (int s = 0; s < 4; ++s)
    #pragma unroll
    for (int e = 0; e < 8; ++e) agg[s][e] = 0.f;

  auto accum = [&](uint4 v, int s, float ns){
    const float2 f0 = bfpair(v.x), f1 = bfpair(v.y);
    const float2 f2 = bfpair(v.z), f3 = bfpair(v.w);
    agg[s][0] = fmaf(f0.x, ns, agg[s][0]);
    agg[s][1] = fmaf(f0.y, ns, agg[s][1]);
    agg[s][2] = fmaf(f1.x, ns, agg[s][2]);
    agg[s][3] = fmaf(f1.y, ns, agg[s][3]);
    agg[s][4] = fmaf(f2.x, ns, agg[s][4]);
    agg[s][5] = fmaf(f2.y, ns, agg[s][5]);
    agg[s][6] = fmaf(f3.x, ns, agg[s][6]);
    agg[s][7] = fmaf(f3.y, ns, agg[s][7]);
  };
  auto gatherN = [&](const u16* ph, float ns){
    const uint4 v0 = *(const uint4*)(ph);
    const uint4 v1 = *(const uint4*)(ph + 32);
    const uint4 v2 = *(const uint4*)(ph + 64);
    const uint4 v3 = *(const uint4*)(ph + 96);
    accum(v0, 0, ns); accum(v1, 1, ns); accum(v2, 2, ns); accum(v3, 3, ns);
  };

  int p0 = 0, p1 = 0;
  if (rok){ p0 = row_ptr[row]; p1 = row_ptr[row+1]; }
  int p = p0;
  #pragma unroll 1
  for (; p + 3 < p1; p += 4){
    const int s0 = col[p], s1 = col[p+1], s2 = col[p+2], s3 = col[p+3];
    const float n0 = norm_s[s0], n1 = norm_s[s1], n2 = norm_s[s2], n3 = norm_s[s3];
    gatherN(h1 + (size_t)s0*HID + kb, n0);
    gatherN(h1 + (size_t)s1*HID + kb, n1);
    gatherN(h1 + (size_t)s2*HID + kb, n2);
    gatherN(h1 + (size_t)s3*HID + kb, n3);
  }
  #pragma unroll 1
  for (; p + 1 < p1; p += 2){
    const int s0 = col[p], s1 = col[p+1];
    const float n0 = norm_s[s0], n1 = norm_s[s1];
    gatherN(h1 + (size_t)s0*HID + kb, n0);
    gatherN(h1 + (size_t)s1*HID + kb, n1);
  }
  if (p < p1){
    const int s0 = col[p];
    gatherN(h1 + (size_t)s0*HID + kb, norm_s[s0]);
  }

  const float nd = rok ? norm_d[row] : 0.f;
  bf16x8 ag[4];
  #pragma unroll
  for (int s = 0; s < 4; ++s)
    #pragma unroll
    for (int e = 0; e < 8; ++e) ag[s][e] = (__bf16)(agg[s][e]*nd);

  const int rA = rok ? row : (n-1);
  const u16* phr = h1 + (size_t)rA*HID + kb;

  f32x4 accg[8], accr[8];
  #pragma unroll
  for (int t = 0; t < 8; ++t){
    accg[t] = f32x4{0.f,0.f,0.f,0.f};
    accr[t] = f32x4{0.f,0.f,0.f,0.f};
  }
  constexpr int FR2 = 8*4*512;
  #pragma unroll
  for (int s = 0; s < 4; ++s){
    const bf16x8 arf = __builtin_bit_cast(bf16x8, *(const s16x8*)(phr + s*32));
    #pragma unroll
    for (int t = 0; t < 8; ++t){
      const bf16x8 bg = __builtin_bit_cast(bf16x8,
          *(const s16x8*)&Bp[((t*4 + s)*64 + lane)*8]);
      const bf16x8 br = __builtin_bit_cast(bf16x8,
          *(const s16x8*)&Bp[FR2 + ((t*4 + s)*64 + lane)*8]);
      accg[t] = __builtin_amdgcn_mfma_f32_16x16x32_bf16(ag[s], bg, accg[t], 0,0,0);
      accr[t] = __builtin_amdgcn_mfma_f32_16x16x32_bf16(arf, br, accr[t], 0,0,0);
    }
  }

  // epilogue: h2 in registers -> fused WeightedSumAndMax readout.
  float o[8][4];
  #pragma unroll
  for (int t = 0; t < 8; ++t){
    const int colc = t*16 + jg;
    const float bgv = bg_[colc], brv = br_[colc];
    #pragma unroll
    for (int r = 0; r < 4; ++r)
      o[t][r] = fmaxf(accg[t][r] + bgv, 0.f) + fmaxf(accr[t][r] + brv, 0.f);
  }
  if (r0 < n){
    float wa[8];
    #pragma unroll
    for (int t = 0; t < 8; ++t) wa[t] = w_atom[t*16 + jg];
    const float ba = b_atom[0];
    const int rowb = r0 + 4*kg;
    float awv[4]; int gidr[4];
    #pragma unroll
    for (int r = 0; r < 4; ++r){
      const int row2 = rowb + r;
      float dot = 0.f;
      #pragma unroll
      for (int t = 0; t < 8; ++t) dot = fmaf(o[t][r], wa[t], dot);
      dot += __shfl_xor(dot, 1);
      dot += __shfl_xor(dot, 2);
      dot += __shfl_xor(dot, 4);
      dot += __shfl_xor(dot, 8);
      awv[r]  = 1.0f/(1.0f + __expf(-(dot + ba)));
      gidr[r] = (row2 < n) ? gid[row2] : -1;
    }
    const int rhi    = (r0 + 15 < n) ? (r0 + 15) : (n - 1);
    const int gfirst = gid[r0];
    const int glast  = gid[rhi];
    for (int g = gfirst; g <= glast; ++g){
      #pragma unroll
      for (int t = 0; t < 8; ++t){
        float sv = 0.f, mv = 0.f;
        #pragma unroll
        for (int r = 0; r < 4; ++r){
          const bool in = (gidr[r] == g);
          sv += in ? o[t][r]*awv[r] : 0.f;
          mv  = in ? fmaxf(mv, o[t][r]) : mv;
        }
        sv += __shfl_xor(sv, 16);
        sv += __shfl_xor(sv, 32);
        mv  = fmaxf(mv, __shfl_xor(mv, 16));
        mv  = fmaxf(mv, __shfl_xor(mv, 32));
        if (lane < 16){
          atomicAdd(&hsum[(size_t)g*HID + t*16 + jg], sv);
          atomicMax(&hmax[(size_t)g*HID + t*16 + jg], __float_as_uint(mv));  // o >= 0
        }
      }
    }
  }
}

// ---------------- fused MLP: latent = relu(gfeat@Wp1+bp1)@Wp2+bp2, zero-row insert
__global__ __launch_bounds__(256) void k_mlp(
    const float* __restrict__ hsum, const float* __restrict__ hmaxf,
    const float* __restrict__ Wp1, const float* __restrict__ bp1,
    const float* __restrict__ Wp2, const float* __restrict__ bp2,
    const int* __restrict__ idxw, int K_,
    float* __restrict__ out, int G_){
  const int lane = threadIdx.x & 63;
  const int row = blockIdx.x*4 + (threadIdx.x >> 6);
  if (blockIdx.x == 0){
    for (int j = 0; j < K_; ++j){
      const int zr = idxw[j];
      for (int i = threadIdx.x; i < DIM; i += 256)
        out[(size_t)zr*DIM + i] = 0.f;
    }
  }
  if (row >= G_) return;
  const int c = lane*2;
  // stage 1: hid cols {c, c+1} per lane
  float ra0 = hsum [(size_t)row*HID + lane];
  float ra1 = hsum [(size_t)row*HID + 64 + lane];
  float ra2 = hmaxf[(size_t)row*HID + lane];
  float ra3 = hmaxf[(size_t)row*HID + 64 + lane];
  float a0 = 0.f, a1 = 0.f;
  #pragma unroll 4
  for (int k = 0; k < 64; ++k){
    const float v0 = rdl(ra0,k), v1 = rdl(ra1,k), v2 = rdl(ra2,k), v3 = rdl(ra3,k);
    const float2 w0 = *(const float2*)&Wp1[(size_t)(k      )*HID + c];
    const float2 w1 = *(const float2*)&Wp1[(size_t)(k +  64)*HID + c];
    const float2 w2 = *(const float2*)&Wp1[(size_t)(k + 128)*HID + c];
    const float2 w3 = *(const float2*)&Wp1[(size_t)(k + 192)*HID + c];
    a0 = fmaf(v0,w0.x, fmaf(v1,w1.x, fmaf(v2,w2.x, fmaf(v3,w3.x, a0))));
    a1 = fmaf(v0,w0.y, fmaf(v1,w1.y, fmaf(v2,w2.y, fmaf(v3,w3.y, a1))));
  }
  const float h0  = fmaxf(a0 + bp1[c],   0.f);   // hid[2*lane]
  const float h1v = fmaxf(a1 + bp1[c+1], 0.f);   // hid[2*lane+1]
  // stage 2: out cols {c4..c4+3}; hid[2j] lives in lane j (h0), hid[2j+1] in h1v
  const int c4 = lane*4;
  float acc0=0.f, acc1=0.f, acc2=0.f, acc3=0.f;
  #pragma unroll 4
  for (int j = 0; j < 64; ++j){
    const float he = rdl(h0, j);
    const float ho = rdl(h1v, j);
    const float4 we = *(const float4*)&Wp2[(size_t)(2*j  )*DIM + c4];
    const float4 wo = *(const float4*)&Wp2[(size_t)(2*j+1)*DIM + c4];
    acc0 = fmaf(he,we.x, fmaf(ho,wo.x, acc0));
    acc1 = fmaf(he,we.y, fmaf(ho,wo.y, acc1));
    acc2 = fmaf(he,we.z, fmaf(ho,wo.z, acc2));
    acc3 = fmaf(he,we.w, fmaf(ho,wo.w, acc3));
  }
  int orow = row;
  for (int j = 0; j < K_; ++j){ if (idxw[j] <= orow) orow++; }
  float* po = out + (size_t)orow*DIM + c4;
  po[0] = acc0 + bp2[c4];
  po[1] = acc1 + bp2[c4+1];
  po[2] = acc2 + bp2[c4+2];
  po[3] = acc3 + bp2[c4+3];
}

extern "C" void kernel_launch(void* const* d_in, const int* in_sizes, int n_in,
                              void* d_out, int out_size, void* d_ws, size_t ws_size,
                              hipStream_t stream){
  (void)n_in; (void)ws_size;
  const float* x0     = (const float*)d_in[0];
  // d_in[1] = edge_feats (unused by the reference GCN)
  const float* W1     = (const float*)d_in[2];
  const float* b1     = (const float*)d_in[3];
  const float* Wr1    = (const float*)d_in[4];
  const float* br1    = (const float*)d_in[5];
  const float* W2     = (const float*)d_in[6];
  const float* b2     = (const float*)d_in[7];
  const float* Wr2    = (const float*)d_in[8];
  const float* br2    = (const float*)d_in[9];
  const float* w_atom = (const float*)d_in[10];
  const float* b_atom = (const float*)d_in[11];
  const float* Wp1    = (const float*)d_in[12];
  const float* bp1    = (const float*)d_in[13];
  const float* Wp2    = (const float*)d_in[14];
  const float* bp2    = (const float*)d_in[15];
  const int* src  = (const int*)d_in[16];
  const int* dst  = (const int*)d_in[17];
  const int* gid  = (const int*)d_in[18];
  const int* idxw = (const int*)d_in[19];

  const int N_ = in_sizes[0] / NODE_F;
  const int E_ = in_sizes[16];
  const int K_ = in_sizes[19];
  const int G_ = out_size / DIM - K_;

  // workspace (~31 MB):
  //  [h1 bf16 N*128][norm_d N]
  //  zero-region: [norm_s N][hsum G*128][hmax G*128][indeg N]
  //  [row_ptr N+1 pad][col E][bsum nscan]
  u16*   h1     = (u16*)d_ws;                          // N*128 u16
  float* norm_d = (float*)(h1 + (size_t)N_*HID);
  float* norm_s = norm_d + N_;
  float* hsum   = norm_s + N_;
  float* hmaxv  = hsum + (size_t)G_*HID;
  int*   indeg  = (int*)(hmaxv + (size_t)G_*HID);
  int*   row_ptr= indeg + N_;
  int*   col    = row_ptr + ((N_ + 4) & ~3);
  int*   bsum   = col + ((E_ + 4) & ~3);
  // weight-fragment scratch lives in d_out (frags = 112 KB << out_size);
  // fully overwritten by k_mlp afterwards (no d_out memset needed).
  u16*   Bp1    = (u16*)d_out;                         // 2*12288 u16
  u16*   Bp2    = Bp1 + 2*12288;                       // 2*16384 u16

  // one contiguous zero region: norm_s + hsum + hmax + indeg
  hipMemsetAsync(norm_s, 0, ((size_t)2*N_ + (size_t)2*G_*HID)*sizeof(float), stream);

  const int nscan = (N_ + 1023)/1024;
  k_deg     <<<(E_+255)/256, 256, 0, stream>>>(src, dst, norm_s, indeg, E_);
  k_scan_a  <<<nscan, 256, 0, stream>>>(indeg, norm_s, norm_d, bsum, N_);
  k_scan_b  <<<1, 1024, 0, stream>>>(bsum, nscan);
  k_scan_c  <<<nscan, 256, 0, stream>>>(indeg, bsum, row_ptr, N_);
  k_fill    <<<(E_+255)/256, 256, 0, stream>>>(src, dst, row_ptr, indeg, col, E_);
  k_prep_all<<<(57344+255)/256, 256, 0, stream>>>(W1, Wr1, W2, Wr2, Bp1, Bp2);

  const int nb = (N_ + 63) / 64;
  k_fgemm1<<<nb, 256, 0, stream>>>(x0, row_ptr, col, norm_s, norm_d,
                                   Bp1, b1, br1, h1, N_);
  k_fgemm2<<<nb, 256, 0, stream>>>(h1, row_ptr, col, norm_s, norm_d,
                                   Bp2, b2, br2, w_atom, b_atom, gid,
                                   hsum, (u32*)hmaxv, N_);

  k_mlp<<<(G_+3)/4, 256, 0, stream>>>(hsum, hmaxv, Wp1, bp1, Wp2, bp2,
                                      idxw, K_, (float*)d_out, G_);
}